// Round 4
// baseline (2361.668 us; speedup 1.0000x reference)
//
#include <hip/hip_runtime.h>

typedef __bf16 bf16;
typedef float f32x4 __attribute__((ext_vector_type(4)));
typedef bf16 bf16x8 __attribute__((ext_vector_type(8)));

#define NTOK 6272
#define DMODEL 1152

// ---------- per-token geometry (GRID = [[1,48,48],[1,32,64],[2,24,40]]) ----------
__device__ __forceinline__ void tok_geo(int t, int& row, int& col, int& gh, int& gw) {
    int local;
    if (t < 2304)      { local = t;        gh = 48; gw = 48; }
    else if (t < 4352) { local = t - 2304; gh = 32; gw = 64; }
    else if (t < 5312) { local = t - 4352; gh = 24; gw = 40; }
    else               { local = t - 5312; gh = 24; gw = 40; }
    int mc = local & 1;
    int mr = (local >> 1) & 1;
    int rest = local >> 2;
    int mwc = gw >> 1;
    int mw = rest % mwc;
    int mh = rest / mwc;
    row = mh * 2 + mr;
    col = mw * 2 + mc;
}

__device__ __forceinline__ float gelu_tanh(float v) {
    float c = v + 0.044715f * v * v * v;
    return 0.5f * v * (1.0f + tanhf(0.7978845608028654f * c));
}

// ---------- runtime dtype detection: fp32 mantissa halves have wild bf16 exponents ----------
__global__ void detect_kernel(const unsigned short* __restrict__ px, int* __restrict__ flag) {
    int tid = threadIdx.x; // 64 threads
    int cnt = 0;
    for (int i = tid * 8; i < tid * 8 + 8; i++) {
        unsigned e = (px[i] >> 7) & 0xFF;
        if (e < 100u || e > 140u) cnt++;
    }
#pragma unroll
    for (int off = 32; off > 0; off >>= 1) cnt += __shfl_down(cnt, off);
    if (tid == 0) *flag = (cnt > 64) ? 1 : 0;  // 1 = inputs are fp32
}

// load 8 elements (any float type) -> 8 bf16 in regs; zero-fill if !pred
template <typename T>
__device__ __forceinline__ void load8(const T* src, bf16* dst, bool pred) {
    if (!pred) {
        uint4 z = {0, 0, 0, 0};
        *(uint4*)dst = z;
        return;
    }
    if constexpr (sizeof(T) == 2) {
        *(uint4*)dst = *(const uint4*)src;
    } else {
        float4 a = *(const float4*)src;
        float4 b = *(const float4*)(src + 4);
        dst[0] = (bf16)a.x; dst[1] = (bf16)a.y; dst[2] = (bf16)a.z; dst[3] = (bf16)a.w;
        dst[4] = (bf16)b.x; dst[5] = (bf16)b.y; dst[6] = (bf16)b.z; dst[7] = (bf16)b.w;
    }
}

// ---------- pos embed (bilinear interp of 48x48 table) -> initializes bf16 x ----------
template <typename TI>
__global__ __launch_bounds__(256) void pos_embed_kernel(const int* __restrict__ flag,
                                                        const TI* __restrict__ tab,
                                                        bf16* __restrict__ x) {
    if (*flag != (sizeof(TI) == 4 ? 1 : 0)) return;
    int t = blockIdx.x;
    int row, col, gh, gw;
    tok_geo(t, row, col, gh, gw);
    float hi = row * 47.0f / (gh - 1);
    float wi = col * 47.0f / (gw - 1);
    int hf = (int)hi, wf = (int)wi;
    int hc = min(hf + 1, 47), wc = min(wf + 1, 47);
    float dh = hi - hf, dw = wi - wf;
    float w00 = (1.f - dh) * (1.f - dw);
    float w01 = (1.f - dh) * dw;
    float w10 = dh * (1.f - dw);
    float w11 = dh * dw;
    const TI* p00 = tab + (size_t)(hf * 48 + wf) * DMODEL;
    const TI* p01 = tab + (size_t)(hf * 48 + wc) * DMODEL;
    const TI* p10 = tab + (size_t)(hc * 48 + wf) * DMODEL;
    const TI* p11 = tab + (size_t)(hc * 48 + wc) * DMODEL;
    bf16* xr = x + (size_t)t * DMODEL;
    for (int d = threadIdx.x; d < DMODEL; d += 256)
        xr[d] = (bf16)(w00 * (float)p00[d] + w01 * (float)p01[d] +
                       w10 * (float)p10[d] + w11 * (float)p11[d]);
}

// ---------- LayerNorm: bf16 x row -> bf16 out ----------
template <typename TI>
__global__ __launch_bounds__(256) void ln_kernel(const int* __restrict__ flag,
                                                 const bf16* __restrict__ x,
                                                 const TI* __restrict__ s,
                                                 const TI* __restrict__ b,
                                                 bf16* __restrict__ out) {
    if (*flag != (sizeof(TI) == 4 ? 1 : 0)) return;
    const int row = blockIdx.x;
    const int tid = threadIdx.x;
    __shared__ float red[4];
    const bf16* xr = x + (size_t)row * DMODEL;
    float vals[5];
    int cnt = 0;
    float sum = 0.f;
    for (int i = tid; i < DMODEL; i += 256) { vals[cnt] = (float)xr[i]; sum += vals[cnt]; cnt++; }
#pragma unroll
    for (int off = 32; off > 0; off >>= 1) sum += __shfl_down(sum, off);
    if ((tid & 63) == 0) red[tid >> 6] = sum;
    __syncthreads();
    float mean = (red[0] + red[1] + red[2] + red[3]) * (1.0f / DMODEL);
    float vs = 0.f;
    for (int i = 0; i < cnt; i++) { float d = vals[i] - mean; vs += d * d; }
#pragma unroll
    for (int off = 32; off > 0; off >>= 1) vs += __shfl_down(vs, off);
    __syncthreads();
    if ((tid & 63) == 0) red[tid >> 6] = vs;
    __syncthreads();
    float var = (red[0] + red[1] + red[2] + red[3]) * (1.0f / DMODEL);
    float inv = rsqrtf(var + 1e-6f);
    int idx = 0;
    for (int i = tid; i < DMODEL; i += 256)
        out[(size_t)row * DMODEL + i] = (bf16)((vals[idx++] - mean) * inv * (float)s[i] + (float)b[i]);
}

// ---------- RoPE in-place on qkv[N,3,16,72]: thread owns pair (j, j+36) of q and k ----------
__global__ __launch_bounds__(256) void rope_inplace_kernel(bf16* __restrict__ qkv) {
    int idx = blockIdx.x * 256 + threadIdx.x;
    const int total = NTOK * 16 * 36;
    if (idx >= total) return;
    int j = idx % 36;
    int rest = idx / 36;
    int h = rest & 15;
    int t = rest >> 4;
    bf16* base = qkv + (size_t)t * 3456 + h * 72;
    int row, col, gh, gw;
    tok_geo(t, row, col, gh, gw);
    float pos = (float)((j < 18) ? row : col);
    int fi = (j < 18) ? j : j - 18;
    float ang = pos * powf(10000.0f, -(float)fi / 18.0f);
    float cv = cosf(ang), sv = sinf(ang);
    float q0v = (float)base[j],        q1v = (float)base[j + 36];
    float k0v = (float)base[1152 + j], k1v = (float)base[1152 + j + 36];
    base[j]          = (bf16)(q0v * cv - q1v * sv);
    base[j + 36]     = (bf16)(q1v * cv + q0v * sv);
    base[1152 + j]      = (bf16)(k0v * cv - k1v * sv);
    base[1152 + j + 36] = (bf16)(k1v * cv + k0v * sv);
}

// ---------- flash attention v3: Q-frags in regs, single-pointer K/V reg-prefetch ----------
// Round-3 spill fix: one staging pointer (V = K + 1152 elems via imm offset), 576-chunk
// packed map, plain launch bounds (no VGPR cap -> no scratch).
__global__ __launch_bounds__(256) void attn_kernel(const bf16* __restrict__ qkv,
                                                   bf16* __restrict__ outp) {
    const int bx = blockIdx.x;
    const int head = bx & 15;
    const int qt = bx >> 4;
    int sbase, slen, qtb;
    if (qt < 36)      { sbase = 0;    slen = 2304; qtb = 0;  }
    else if (qt < 68) { sbase = 2304; slen = 2048; qtb = 36; }
    else if (qt < 83) { sbase = 4352; slen = 960;  qtb = 68; }
    else              { sbase = 5312; slen = 960;  qtb = 83; }
    const int q0 = sbase + (qt - qtb) * 64;

    __shared__ bf16 Ks[64][104];  // also used to stage Q once at entry
    __shared__ bf16 Vs[80][72];   // [feature][kv]
    __shared__ bf16 Ps[64][72];

    const int tid = threadIdx.x;
    const int wv = tid >> 6;
    const int lane = tid & 63;
    const int quad = lane >> 4;
    const int l15 = lane & 15;

    const size_t hoff = (size_t)head * 72;

    // zero pad Vs feature rows 72..79 (cols 0..63 are all PV reads) -- ONCE
    for (int c = tid; c < 64; c += 256) {
        int r = 72 + (c >> 3), cc = (c & 7) * 8;
        uint4 z = {0, 0, 0, 0};
        *(uint4*)&Vs[r][cc] = z;
    }

    // stage Q tile into Ks (zero-pad cols 72..95), then hoist per-wave Q fragments to regs
    for (int c = tid; c < 768; c += 256) {
        int r = c / 12, cc = (c % 12) * 8;
        uint4 v = {0, 0, 0, 0};
        if (cc < 72) v = *(const uint4*)(qkv + (size_t)(q0 + r) * 3456 + hoff + cc);
        *(uint4*)&Ks[r][cc] = v;
    }
    __syncthreads();
    bf16x8 aq[3];
#pragma unroll
    for (int i = 0; i < 3; i++) aq[i] = *(const bf16x8*)&Ks[wv * 16 + l15][i * 32 + quad * 8];

    // ---- staging map: chunk c = tid + 256j (j=0,1; j=2 only tid<64), all 576 real ----
    //   row = lane, col chunk cc_j = (wv + 4j)*8  [j=2 -> cc=64, wv==0 only]
    // One pointer; K chunks at +0/+64/+128 B, V chunks at +2304/+2368/+2432 B (imm offsets).
    const int cc0 = wv * 8;
    const bool w0 = tid < 64;  // owns the j=2 chunk (col 64..71)
    const bf16* kp = qkv + (size_t)(sbase + lane) * 3456 + 1152 + hoff + cc0;
    const int stepE = 64 * 3456;  // elements per kv-tile step

    // ---- preload tile 0 into regs ----
    uint4 kr0, kr1, kr2, vr0, vr1, vr2;
    kr0 = *(const uint4*)kp;
    kr1 = *(const uint4*)(kp + 32);
    vr0 = *(const uint4*)(kp + 1152);
    vr1 = *(const uint4*)(kp + 1184);
    if (w0) {
        kr2 = *(const uint4*)(kp + 64);
        vr2 = *(const uint4*)(kp + 1216);
    }
    kp += stepE;

    f32x4 o[5] = {};
    float m_i[4], l_i[4];
#pragma unroll
    for (int r = 0; r < 4; r++) { m_i[r] = -1e30f; l_i[r] = 0.f; }

    const float C1 = 0.17002234f;  // 72^-0.5 * log2(e)
    const int nkv = slen >> 6;
    for (int kt = 0; kt < nkv; kt++) {
        __syncthreads();  // barrier A: prior step's LDS reads (and entry aq reads) done
        // regs -> LDS (K: vector rows; V: transposed scalar writes, conflict-free kv-major)
        *(uint4*)&Ks[lane][cc0] = kr0;
        *(uint4*)&Ks[lane][cc0 + 32] = kr1;
        if (w0) *(uint4*)&Ks[lane][64] = kr2;
        {
            const bf16* e = (const bf16*)&vr0;
#pragma unroll
            for (int i = 0; i < 8; i++) Vs[cc0 + i][lane] = e[i];
        }
        {
            const bf16* e = (const bf16*)&vr1;
#pragma unroll
            for (int i = 0; i < 8; i++) Vs[cc0 + 32 + i][lane] = e[i];
        }
        if (w0) {
            const bf16* e = (const bf16*)&vr2;
#pragma unroll
            for (int i = 0; i < 8; i++) Vs[64 + i][lane] = e[i];
        }
        __syncthreads();  // barrier B: tile staged

        // issue next tile's global loads; latency hides under QK+softmax+PV
        if (kt + 1 < nkv) {
            kr0 = *(const uint4*)kp;
            kr1 = *(const uint4*)(kp + 32);
            vr0 = *(const uint4*)(kp + 1152);
            vr1 = *(const uint4*)(kp + 1184);
            if (w0) {
                kr2 = *(const uint4*)(kp + 64);
                vr2 = *(const uint4*)(kp + 1216);
            }
            kp += stepE;
        }

        // S = Q K^T (raw, scale folded into exp2 below)
        f32x4 sfr[4] = {};
#pragma unroll
        for (int kc = 0; kc < 3; kc++)
#pragma unroll
            for (int nt = 0; nt < 4; nt++) {
                bf16x8 bk = *(const bf16x8*)&Ks[nt * 16 + l15][kc * 32 + quad * 8];
                sfr[nt] = __builtin_amdgcn_mfma_f32_16x16x32_bf16(aq[kc], bk, sfr[nt], 0, 0, 0);
            }

        // online softmax; row = quad*4+reg, 16 lanes of the quad share a row
        float mx[4];
#pragma unroll
        for (int reg = 0; reg < 4; reg++) {
            float m = fmaxf(fmaxf(sfr[0][reg], sfr[1][reg]), fmaxf(sfr[2][reg], sfr[3][reg]));
            m = fmaxf(m, __shfl_xor(m, 1));
            m = fmaxf(m, __shfl_xor(m, 2));
            m = fmaxf(m, __shfl_xor(m, 4));
            m = fmaxf(m, __shfl_xor(m, 8));
            mx[reg] = m;
        }
        // defer-max: rescale only when some row max grew (wave-uniform branch)
        bool grow = (mx[0] > m_i[0]) || (mx[1] > m_i[1]) || (mx[2] > m_i[2]) || (mx[3] > m_i[3]);
        if (__any(grow)) {
#pragma unroll
            for (int reg = 0; reg < 4; reg++) {
                float mn = fmaxf(m_i[reg], mx[reg]);
                float a = __builtin_amdgcn_exp2f((m_i[reg] - mn) * C1);
                m_i[reg] = mn;
                l_i[reg] *= a;
#pragma unroll
                for (int nt = 0; nt < 5; nt++) o[nt][reg] *= a;
            }
        }
        float mc[4];
#pragma unroll
        for (int reg = 0; reg < 4; reg++) mc[reg] = m_i[reg] * C1;
        float rs[4] = {0.f, 0.f, 0.f, 0.f};
#pragma unroll
        for (int nt = 0; nt < 4; nt++)
#pragma unroll
            for (int reg = 0; reg < 4; reg++) {
                float p = __builtin_amdgcn_exp2f(fmaf(sfr[nt][reg], C1, -mc[reg]));
                sfr[nt][reg] = p;
                rs[reg] += p;
            }
#pragma unroll
        for (int reg = 0; reg < 4; reg++) {
            float r = rs[reg];
            r += __shfl_xor(r, 1);
            r += __shfl_xor(r, 2);
            r += __shfl_xor(r, 4);
            r += __shfl_xor(r, 8);
            l_i[reg] += r;
        }

        // P: C-layout -> LDS. Ps rows [wv*16, wv*16+16) are wave-private: no barrier,
        // lgkmcnt ordering (compiler-inserted) suffices before the reads below.
#pragma unroll
        for (int nt = 0; nt < 4; nt++)
#pragma unroll
            for (int reg = 0; reg < 4; reg++)
                Ps[wv * 16 + quad * 4 + reg][nt * 16 + l15] = (bf16)sfr[nt][reg];

        // O += P @ V
#pragma unroll
        for (int kc = 0; kc < 2; kc++) {
            bf16x8 ap = *(const bf16x8*)&Ps[wv * 16 + l15][kc * 32 + quad * 8];
#pragma unroll
            for (int nt = 0; nt < 5; nt++) {
                bf16x8 bv = *(const bf16x8*)&Vs[nt * 16 + l15][kc * 32 + quad * 8];
                o[nt] = __builtin_amdgcn_mfma_f32_16x16x32_bf16(ap, bv, o[nt], 0, 0, 0);
            }
        }
    }

#pragma unroll
    for (int nt = 0; nt < 5; nt++)
#pragma unroll
        for (int reg = 0; reg < 4; reg++) {
            int c = nt * 16 + l15;
            if (c < 72) {
                int tok = q0 + wv * 16 + quad * 4 + reg;
                outp[(size_t)tok * DMODEL + head * 72 + c] = (bf16)(o[nt][reg] / l_i[reg]);
            }
        }
}

// ---------- OLD generic GEMM (fallback path when workspace too small) ----------
template <int MODE, typename TA, typename TB>
__global__ __launch_bounds__(256) void gemm_kernel(const int* __restrict__ flag,
                                                   const TA* __restrict__ A,
                                                   const TB* __restrict__ B,
                                                   const TB* __restrict__ bias,
                                                   void* __restrict__ outp,
                                                   int M, int N, int K) {
    if (*flag != (sizeof(TB) == 4 ? 1 : 0)) return;
    __shared__ bf16 As[128][40];
    __shared__ bf16 Bs[128][40];
    const int tid = threadIdx.x;
    const int m0 = blockIdx.y * 128;
    const int n0 = blockIdx.x * 128;
    const int wv = tid >> 6;
    const int lane = tid & 63;
    const int quad = lane >> 4;
    const int l15 = lane & 15;
    const int wr = (wv >> 1) * 64;
    const int wc = (wv & 1) * 64;

    const int a_row = tid >> 1;
    const int a_col = (tid & 1) * 16;
    const int b_k = tid & 31;
    const int b_n = (tid >> 5) * 16;

    f32x4 acc[4][4] = {};

    for (int k0 = 0; k0 < K; k0 += 32) {
        __syncthreads();
        {
            bf16 ea[16];
            int gr = m0 + a_row;
            const TA* ap = A + (size_t)gr * K + k0 + a_col;
            load8(ap, ea, gr < M && (k0 + a_col) < K);
            load8(ap + 8, ea + 8, gr < M && (k0 + a_col + 8) < K);
            *(uint4*)&As[a_row][a_col] = *(uint4*)ea;
            *(uint4*)&As[a_row][a_col + 8] = *(uint4*)(ea + 8);
        }
        {
            bf16 eb[16];
            int gk = k0 + b_k;
            const TB* bp = B + (size_t)gk * N + n0 + b_n;
            load8(bp, eb, gk < K && (n0 + b_n) < N);
            load8(bp + 8, eb + 8, gk < K && (n0 + b_n + 8) < N);
#pragma unroll
            for (int i = 0; i < 16; i++) Bs[b_n + i][b_k] = eb[i];
        }
        __syncthreads();

        bf16x8 af[4], bfv[4];
#pragma unroll
        for (int mi = 0; mi < 4; mi++) af[mi] = *(const bf16x8*)&As[wr + mi * 16 + l15][quad * 8];
#pragma unroll
        for (int ni = 0; ni < 4; ni++) bfv[ni] = *(const bf16x8*)&Bs[wc + ni * 16 + l15][quad * 8];
#pragma unroll
        for (int mi = 0; mi < 4; mi++)
#pragma unroll
            for (int ni = 0; ni < 4; ni++)
                acc[mi][ni] = __builtin_amdgcn_mfma_f32_16x16x32_bf16(af[mi], bfv[ni], acc[mi][ni], 0, 0, 0);
    }

#pragma unroll
    for (int mi = 0; mi < 4; mi++) {
#pragma unroll
        for (int ni = 0; ni < 4; ni++) {
#pragma unroll
            for (int reg = 0; reg < 4; reg++) {
                int r = m0 + wr + mi * 16 + quad * 4 + reg;
                int c = n0 + wc + ni * 16 + l15;
                if (r < M && c < N) {
                    float v = acc[mi][ni][reg] + (float)bias[c];
                    if (MODE == 1) v = gelu_tanh(v);
                    if (MODE == 2) {
                        bf16* o = (bf16*)outp;
                        size_t idx = (size_t)r * N + c;
                        o[idx] = (bf16)((float)o[idx] + v);
                    } else if (MODE == 3) {
                        TB* o = (TB*)outp;
                        o[(size_t)r * N + c] = (TB)v;
                    } else {
                        bf16* o = (bf16*)outp;
                        o[(size_t)r * N + c] = (bf16)v;
                    }
                }
            }
        }
    }
}

// ================= pre-transposed bf16 weights + global_load_lds GEMM =================

// flat dtype convert (pixels): n8 chunks of 8 elements
template <typename TI>
__global__ __launch_bounds__(256) void cvt_kernel(const int* __restrict__ flag,
                                                  const TI* __restrict__ in,
                                                  bf16* __restrict__ out, int n8) {
    if (*flag != (sizeof(TI) == 4 ? 1 : 0)) return;
    for (int i = blockIdx.x * 256 + threadIdx.x; i < n8; i += gridDim.x * 256) {
        bf16 e[8];
        load8(in + (size_t)i * 8, e, true);
        *(uint4*)(out + (size_t)i * 8) = *(uint4*)e;
    }
}

// transpose+convert weight: B[K][N] (TI) -> T[N][Kpad] (bf16), zero-padded k in [K,Kpad)
template <typename TI>
__global__ __launch_bounds__(256) void transpose_w_kernel(const int* __restrict__ flag,
                                                          const TI* __restrict__ B,
                                                          bf16* __restrict__ T,
                                                          int K, int N, int Kpad) {
    if (*flag != (sizeof(TI) == 4 ? 1 : 0)) return;
    __shared__ bf16 t[64][72];
    const int k0 = blockIdx.y * 64, n0 = blockIdx.x * 64;
    const int tid = threadIdx.x;
    const int kk = tid >> 2;
    const int nn0 = (tid & 3) * 16;
    bf16 e[16];
    bool ok = (k0 + kk < K) && (n0 + nn0 < N);  // N is a multiple of 16
    const TI* src = B + (size_t)(k0 + kk) * N + n0 + nn0;
    load8(src, e, ok);
    load8(src + 8, e + 8, ok);
#pragma unroll
    for (int i = 0; i < 16; i++) t[nn0 + i][kk] = e[i];
    __syncthreads();
    const int nn = tid >> 2;
    const int j16 = (tid & 3) * 16;
    if (n0 + nn < N && k0 + j16 < Kpad) {  // Kpad multiple of 32 -> full 16 fits
        bf16* dst = T + (size_t)(n0 + nn) * Kpad + k0 + j16;
        *(uint4*)dst = *(uint4*)&t[nn][j16];
        *(uint4*)(dst + 8) = *(uint4*)&t[nn][j16 + 8];
    }
}

// convert all 11 GEMM bias vectors into one bf16 arena
template <typename TI>
__global__ __launch_bounds__(256) void cvt_bias_kernel(const int* __restrict__ flag,
        const TI* p0, const TI* p1, const TI* p2, const TI* p3, const TI* p4,
        const TI* p5, const TI* p6, const TI* p7, const TI* p8, const TI* p9,
        const TI* p10, bf16* __restrict__ out) {
    if (*flag != (sizeof(TI) == 4 ? 1 : 0)) return;
    const int lens[11] = {1152, 3456, 3456, 1152, 1152, 4304, 4304, 1152, 1152, 4608, 2048};
    const int offs[11] = {0, 1152, 4608, 8064, 9216, 10368, 14672, 18976, 20128, 21280, 25888};
    int b = blockIdx.x;
    const TI* src = (b == 0) ? p0 : (b == 1) ? p1 : (b == 2) ? p2 : (b == 3) ? p3
                  : (b == 4) ? p4 : (b == 5) ? p5 : (b == 6) ? p6 : (b == 7) ? p7
                  : (b == 8) ? p8 : (b == 9) ? p9 : p10;
    for (int i = threadIdx.x; i < lens[b]; i += 256) out[offs[b] + i] = (bf16)(float)src[i];
}

typedef const __attribute__((address_space(1))) void* gas_ptr;
typedef __attribute__((address_space(3))) void* las_ptr;
__device__ __forceinline__ void gload16(const bf16* g, bf16* l) {
    __builtin_amdgcn_global_load_lds((gas_ptr)g, (las_ptr)l, 16, 0, 0);
}

// m97-style GEMM: C[M,ldc] = A[M,K] @ BT[N,K]^T + bias, global_load_lds staging, linear LDS.
// K must be a multiple of 32 and is also the row stride of A and BT.
// MODE 0: bf16 store; 1: bf16 gelu (zero-fills c in [N,ldc)); 2: bf16 +=; 3: store f32/bf16 by *flag
template <int MODE>
__global__ __launch_bounds__(256) void gemm_lds_kernel(const int* __restrict__ flag,
        const bf16* __restrict__ A, const bf16* __restrict__ BT,
        const bf16* __restrict__ bias, void* __restrict__ outp,
        int M, int N, int K, int ldc) {
    __shared__ bf16 As[128][32];
    __shared__ bf16 Bs[128][32];
    const int tid = threadIdx.x;
    const int m0 = blockIdx.y * 128;
    const int n0 = blockIdx.x * 128;
    const int wv = tid >> 6;
    const int lane = tid & 63;
    const int quad = lane >> 4;
    const int l15 = lane & 15;
    const int wr = (wv >> 1) * 64;
    const int wc = (wv & 1) * 64;

    // staging: wave wv fills LDS rows [wv*32, wv*32+32) of As and Bs via 2+2 global_load_lds.
    const int sr = wv * 32 + (lane >> 2);
    const int sc = (lane & 3) * 8;
    const bf16* aP0 = A + (size_t)min(m0 + sr, M - 1) * K + sc;
    const bf16* aP1 = A + (size_t)min(m0 + sr + 16, M - 1) * K + sc;
    const bf16* bP0 = BT + (size_t)min(n0 + sr, N - 1) * K + sc;
    const bf16* bP1 = BT + (size_t)min(n0 + sr + 16, N - 1) * K + sc;
    bf16* lA0 = &As[wv * 32][0];
    bf16* lA1 = &As[wv * 32 + 16][0];
    bf16* lB0 = &Bs[wv * 32][0];
    bf16* lB1 = &Bs[wv * 32 + 16][0];

    f32x4 acc[4][4] = {};
    for (int k0 = 0; k0 < K; k0 += 32) {
        __syncthreads();
        gload16(aP0 + k0, lA0);
        gload16(aP1 + k0, lA1);
        gload16(bP0 + k0, lB0);
        gload16(bP1 + k0, lB1);
        __syncthreads();
        bf16x8 af[4], bfv[4];
#pragma unroll
        for (int mi = 0; mi < 4; mi++) af[mi] = *(const bf16x8*)&As[wr + mi * 16 + l15][quad * 8];
#pragma unroll
        for (int ni = 0; ni < 4; ni++) bfv[ni] = *(const bf16x8*)&Bs[wc + ni * 16 + l15][quad * 8];
#pragma unroll
        for (int mi = 0; mi < 4; mi++)
#pragma unroll
            for (int ni = 0; ni < 4; ni++)
                acc[mi][ni] = __builtin_amdgcn_mfma_f32_16x16x32_bf16(af[mi], bfv[ni], acc[mi][ni], 0, 0, 0);
    }

    const int isf32 = (MODE == 3) ? *flag : 0;
#pragma unroll
    for (int mi = 0; mi < 4; mi++) {
#pragma unroll
        for (int ni = 0; ni < 4; ni++) {
#pragma unroll
            for (int reg = 0; reg < 4; reg++) {
                int r = m0 + wr + mi * 16 + quad * 4 + reg;
                int c = n0 + wc + ni * 16 + l15;
                if (r < M && c < ldc) {
                    float v = 0.f;
                    if (c < N) {
                        v = acc[mi][ni][reg] + (float)bias[c];
                        if (MODE == 1) v = gelu_tanh(v);
                    }
                    if (MODE == 2) {
                        bf16* o = (bf16*)outp;
                        size_t idx = (size_t)r * ldc + c;
                        o[idx] = (bf16)((float)o[idx] + v);
                    } else if (MODE == 3) {
                        if (isf32) ((float*)outp)[(size_t)r * ldc + c] = v;
                        else       ((bf16*)outp)[(size_t)r * ldc + c] = (bf16)v;
                    } else {
                        ((bf16*)outp)[(size_t)r * ldc + c] = (bf16)v;
                    }
                }
            }
        }
    }
}

// ---------- arena layout (bf16 elements) ----------
#define OFF_PATCH  0ULL
#define OFF_QKV    1769472ULL
#define QKV_SZ     3981312ULL
#define OFF_PROJ   9732096ULL
#define PROJ_SZ    1327104ULL
#define OFF_FC1    12386304ULL
#define FC1_SZ     4958208ULL
#define OFF_FC2    22302720ULL
#define FC2_SZ     4976640ULL
#define OFF_MFC1   32256000ULL
#define OFF_MFC2   53489664ULL
#define OFF_BIAS   62926848ULL
#define WS_NEEDED  209001280ULL

extern "C" void kernel_launch(void* const* d_in, const int* in_sizes, int n_in,
                              void* d_out, int out_size, void* d_ws, size_t ws_size,
                              hipStream_t stream) {
    char* ws = (char*)d_ws;
    int* flag  = (int*)ws;                       // 256 B reserved
    bf16* x    = (bf16*)(ws + 256);              // 14,450,688 B
    bf16* h    = (bf16*)(ws + 256 + 14450688);   // 14,450,688 B
    bf16* bufA = (bf16*)(ws + 256 + 28901376);   // 54,190,080 B (6272*4320*2)

    detect_kernel<<<1, 64, 0, stream>>>((const unsigned short*)d_in[0], flag);

    if (ws_size >= WS_NEEDED) {
        // ---------------- NEW PATH ----------------
        bf16* wT = (bf16*)(ws + 256 + 28901376 + 54190080);
        bf16* bias = wT + OFF_BIAS;
        bf16* px = bufA;  // pixels-as-bf16 live in bufA until the patch GEMM is done

        // pixel convert (6272*1536 / 8 = 1,204,224 chunks)
        cvt_kernel<bf16><<<1024, 256, 0, stream>>>(flag, (const bf16*)d_in[0], px, 1204224);
        cvt_kernel<float><<<1024, 256, 0, stream>>>(flag, (const float*)d_in[0], px, 1204224);

        // weight transposes (both dtype instantiations; only the matching one runs)
        auto T2 = [&](const void* srcBase, size_t eoff, bf16* dst, int K, int N, int Kpad) {
            dim3 g((N + 63) / 64, (Kpad + 63) / 64);
            transpose_w_kernel<bf16><<<g, 256, 0, stream>>>(flag, (const bf16*)srcBase + eoff, dst, K, N, Kpad);
            transpose_w_kernel<float><<<g, 256, 0, stream>>>(flag, (const float*)srcBase + eoff, dst, K, N, Kpad);
        };
        T2(d_in[2], 0, wT + OFF_PATCH, 1536, 1152, 1536);
        for (int l = 0; l < 2; l++) {
            T2(d_in[7],  (size_t)l * 1152 * 3456, wT + OFF_QKV + l * QKV_SZ, 1152, 3456, 1152);
            T2(d_in[9],  (size_t)l * 1152 * 1152, wT + OFF_PROJ + l * PROJ_SZ, 1152, 1152, 1152);
            T2(d_in[13], (size_t)l * 1152 * 4304, wT + OFF_FC1 + l * FC1_SZ, 1152, 4304, 1152);
            T2(d_in[15], (size_t)l * 4304 * 1152, wT + OFF_FC2 + l * FC2_SZ, 4304, 1152, 4320);
        }
        T2(d_in[19], 0, wT + OFF_MFC1, 4608, 4608, 4608);
        T2(d_in[21], 0, wT + OFF_MFC2, 4608, 2048, 4608);

        cvt_bias_kernel<bf16><<<11, 256, 0, stream>>>(flag,
            (const bf16*)d_in[3],
            (const bf16*)d_in[8], (const bf16*)d_in[8] + 3456,
            (const bf16*)d_in[10], (const bf16*)d_in[10] + 1152,
            (const bf16*)d_in[14], (const bf16*)d_in[14] + 4304,
            (const bf16*)d_in[16], (const bf16*)d_in[16] + 1152,
            (const bf16*)d_in[20], (const bf16*)d_in[22], bias);
        cvt_bias_kernel<float><<<11, 256, 0, stream>>>(flag,
            (const float*)d_in[3],
            (const float*)d_in[8], (const float*)d_in[8] + 3456,
            (const float*)d_in[10], (const float*)d_in[10] + 1152,
            (const float*)d_in[14], (const float*)d_in[14] + 4304,
            (const float*)d_in[16], (const float*)d_in[16] + 1152,
            (const float*)d_in[20], (const float*)d_in[22], bias);

        pos_embed_kernel<bf16><<<NTOK, 256, 0, stream>>>(flag, (const bf16*)d_in[4], x);
        pos_embed_kernel<float><<<NTOK, 256, 0, stream>>>(flag, (const float*)d_in[4], x);

        gemm_lds_kernel<2><<<dim3(9, 49), 256, 0, stream>>>(flag, px, wT + OFF_PATCH,
                                                            bias + 0, x, NTOK, 1152, 1536, 1152);

        for (int l = 0; l < 2; l++) {
            ln_kernel<bf16><<<NTOK, 256, 0, stream>>>(flag, x, (const bf16*)d_in[5] + l * 1152,
                                                      (const bf16*)d_in[6] + l * 1152, h);
            ln_kernel<float><<<NTOK, 256, 0, stream>>>(flag, x, (const float*)d_in[5] + l * 1152,
                                                       (const float*)d_in[6] + l * 1152, h);
            gemm_lds_kernel<0><<<dim3(27, 49), 256, 0, stream>>>(flag, h, wT + OFF_QKV + l * QKV_SZ,
                                                                 bias + 1152 + l * 3456, bufA,
                                                                 NTOK, 3456, 1152, 3456);
            rope_inplace_kernel<<<(NTOK * 16 * 36 + 255) / 256, 256, 0, stream>>>(bufA);
            attn_kernel<<<98 * 16, 256, 0, stream>>>(bufA, h);
            gemm_lds_kernel<2><<<dim3(9, 49), 256, 0, stream>>>(flag, h, wT + OFF_PROJ + l * PROJ_SZ,
                                                                bias + 8064 + l * 1152, x,
                                                                NTOK, 1152, 1152, 1152);
            ln_kernel<bf16><<<NTOK, 256, 0, stream>>>(flag, x, (const bf16*)d_in[11] + l * 1152,
                                                      (const bf16*)d_in[12] + l * 1152, h);
            ln_kernel<float><<<NTOK, 256, 0, stream>>>(flag, x, (const float*)d_in[11] + l * 1152,
                                                       (const float*)d_in[12] + l * 1152, h);
            // fc1: ldc=4320, zero-fills pad cols so fc2 can run K=4320
            gemm_lds_kernel<1><<<dim3(34, 49), 256, 0, stream>>>(flag, h, wT + OFF_FC1 + l * FC1_SZ,
                                                                 bias + 10368 + l * 4304, bufA,
                                                                 NTOK, 4304, 1152, 4320);
            gemm_lds_kernel<2><<<dim3(9, 49), 256, 0, stream>>>(flag, bufA, wT + OFF_FC2 + l * FC2_SZ,
                                                                bias + 18976 + l * 1152, x,
                                                                NTOK, 1152, 4320, 1152);
        }
        ln_kernel<bf16><<<NTOK, 256, 0, stream>>>(flag, x, (const bf16*)d_in[17], (const bf16*)d_in[18], h);
        ln_kernel<float><<<NTOK, 256, 0, stream>>>(flag, x, (const float*)d_in[17], (const float*)d_in[18], h);
        gemm_lds_kernel<1><<<dim3(36, 13), 256, 0, stream>>>(flag, h, wT + OFF_MFC1,
                                                             bias + 21280, bufA, 1568, 4608, 4608, 4608);
        gemm_lds_kernel<3><<<dim3(16, 13), 256, 0, stream>>>(flag, bufA, wT + OFF_MFC2,
                                                             bias + 25888, d_out, 1568, 2048, 4608, 2048);
        return;
    }

    // ---------------- FALLBACK: round-1 verified path ----------------
    {
        pos_embed_kernel<bf16><<<NTOK, 256, 0, stream>>>(flag, (const bf16*)d_in[4], x);
        pos_embed_kernel<float><<<NTOK, 256, 0, stream>>>(flag, (const float*)d_in[4], x);
        gemm_kernel<2, bf16, bf16><<<dim3(9, 49), 256, 0, stream>>>(
            flag, (const bf16*)d_in[0], (const bf16*)d_in[2], (const bf16*)d_in[3], x, NTOK, 1152, 1536);
        gemm_kernel<2, float, float><<<dim3(9, 49), 256, 0, stream>>>(
            flag, (const float*)d_in[0], (const float*)d_in[2], (const float*)d_in[3], x, NTOK, 1152, 1536);
    }
    for (int l = 0; l < 2; l++) {
        ln_kernel<bf16><<<NTOK, 256, 0, stream>>>(flag, x, (const bf16*)d_in[5] + l * 1152,
                                                  (const bf16*)d_in[6] + l * 1152, h);
        ln_kernel<float><<<NTOK, 256, 0, stream>>>(flag, x, (const float*)d_in[5] + l * 1152,
                                                   (const float*)d_in[6] + l * 1152, h);
        gemm_kernel<0, bf16, bf16><<<dim3(27, 49), 256, 0, stream>>>(
            flag, h, (const bf16*)d_in[7] + (size_t)l * 1152 * 3456,
            (const bf16*)d_in[8] + l * 3456, bufA, NTOK, 3456, 1152);
        gemm_kernel<0, bf16, float><<<dim3(27, 49), 256, 0, stream>>>(
            flag, h, (const float*)d_in[7] + (size_t)l * 1152 * 3456,
            (const float*)d_in[8] + l * 3456, bufA, NTOK, 3456, 1152);
        rope_inplace_kernel<<<(NTOK * 16 * 36 + 255) / 256, 256, 0, stream>>>(bufA);
        attn_kernel<<<98 * 16, 256, 0, stream>>>(bufA, h);
        gemm_kernel<2, bf16, bf16><<<dim3(9, 49), 256, 0, stream>>>(
            flag, h, (const bf16*)d_in[9] + (size_t)l * 1152 * 1152,
            (const bf16*)d_in[10] + l * 1152, x, NTOK, 1152, 1152);
        gemm_kernel<2, bf16, float><<<dim3(9, 49), 256, 0, stream>>>(
            flag, h, (const float*)d_in[9] + (size_t)l * 1152 * 1152,
            (const float*)d_in[10] + l * 1152, x, NTOK, 1152, 1152);
        ln_kernel<bf16><<<NTOK, 256, 0, stream>>>(flag, x, (const bf16*)d_in[11] + l * 1152,
                                                  (const bf16*)d_in[12] + l * 1152, h);
        ln_kernel<float><<<NTOK, 256, 0, stream>>>(flag, x, (const float*)d_in[11] + l * 1152,
                                                   (const float*)d_in[12] + l * 1152, h);
        gemm_kernel<1, bf16, bf16><<<dim3(34, 49), 256, 0, stream>>>(
            flag, h, (const bf16*)d_in[13] + (size_t)l * 1152 * 4304,
            (const bf16*)d_in[14] + l * 4304, bufA, NTOK, 4304, 1152);
        gemm_kernel<1, bf16, float><<<dim3(34, 49), 256, 0, stream>>>(
            flag, h, (const float*)d_in[13] + (size_t)l * 1152 * 4304,
            (const float*)d_in[14] + l * 4304, bufA, NTOK, 4304, 1152);
        gemm_kernel<2, bf16, bf16><<<dim3(9, 49), 256, 0, stream>>>(
            flag, bufA, (const bf16*)d_in[15] + (size_t)l * 4304 * 1152,
            (const bf16*)d_in[16] + l * 1152, x, NTOK, 1152, 4304);
        gemm_kernel<2, bf16, float><<<dim3(9, 49), 256, 0, stream>>>(
            flag, bufA, (const float*)d_in[15] + (size_t)l * 4304 * 1152,
            (const float*)d_in[16] + l * 1152, x, NTOK, 1152, 4304);
    }
    ln_kernel<bf16><<<NTOK, 256, 0, stream>>>(flag, x, (const bf16*)d_in[17], (const bf16*)d_in[18], h);
    ln_kernel<float><<<NTOK, 256, 0, stream>>>(flag, x, (const float*)d_in[17], (const float*)d_in[18], h);
    gemm_kernel<1, bf16, bf16><<<dim3(36, 13), 256, 0, stream>>>(
        flag, h, (const bf16*)d_in[19], (const bf16*)d_in[20], bufA, 1568, 4608, 4608);
    gemm_kernel<1, bf16, float><<<dim3(36, 13), 256, 0, stream>>>(
        flag, h, (const float*)d_in[19], (const float*)d_in[20], bufA, 1568, 4608, 4608);
    gemm_kernel<3, bf16, bf16><<<dim3(16, 13), 256, 0, stream>>>(
        flag, bufA, (const bf16*)d_in[21], (const bf16*)d_in[22], d_out, 1568, 2048, 4608);
    gemm_kernel<3, bf16, float><<<dim3(16, 13), 256, 0, stream>>>(
        flag, bufA, (const float*)d_in[21], (const float*)d_in[22], d_out, 1568, 2048, 4608);
}

// Round 5
// 2211.615 us; speedup vs baseline: 1.0678x; 1.0678x over previous
//
#include <hip/hip_runtime.h>

typedef __bf16 bf16;
typedef float f32x4 __attribute__((ext_vector_type(4)));
typedef bf16 bf16x8 __attribute__((ext_vector_type(8)));

#define NTOK 6272
#define DMODEL 1152

// ---------- per-token geometry (GRID = [[1,48,48],[1,32,64],[2,24,40]]) ----------
__device__ __forceinline__ void tok_geo(int t, int& row, int& col, int& gh, int& gw) {
    int local;
    if (t < 2304)      { local = t;        gh = 48; gw = 48; }
    else if (t < 4352) { local = t - 2304; gh = 32; gw = 64; }
    else if (t < 5312) { local = t - 4352; gh = 24; gw = 40; }
    else               { local = t - 5312; gh = 24; gw = 40; }
    int mc = local & 1;
    int mr = (local >> 1) & 1;
    int rest = local >> 2;
    int mwc = gw >> 1;
    int mw = rest % mwc;
    int mh = rest / mwc;
    row = mh * 2 + mr;
    col = mw * 2 + mc;
}

__device__ __forceinline__ float gelu_tanh(float v) {
    float c = v + 0.044715f * v * v * v;
    return 0.5f * v * (1.0f + tanhf(0.7978845608028654f * c));
}

// ---------- runtime dtype detection: fp32 mantissa halves have wild bf16 exponents ----------
__global__ void detect_kernel(const unsigned short* __restrict__ px, int* __restrict__ flag) {
    int tid = threadIdx.x; // 64 threads
    int cnt = 0;
    for (int i = tid * 8; i < tid * 8 + 8; i++) {
        unsigned e = (px[i] >> 7) & 0xFF;
        if (e < 100u || e > 140u) cnt++;
    }
#pragma unroll
    for (int off = 32; off > 0; off >>= 1) cnt += __shfl_down(cnt, off);
    if (tid == 0) *flag = (cnt > 64) ? 1 : 0;  // 1 = inputs are fp32
}

// load 8 elements (any float type) -> 8 bf16 in regs; zero-fill if !pred
template <typename T>
__device__ __forceinline__ void load8(const T* src, bf16* dst, bool pred) {
    if (!pred) {
        uint4 z = {0, 0, 0, 0};
        *(uint4*)dst = z;
        return;
    }
    if constexpr (sizeof(T) == 2) {
        *(uint4*)dst = *(const uint4*)src;
    } else {
        float4 a = *(const float4*)src;
        float4 b = *(const float4*)(src + 4);
        dst[0] = (bf16)a.x; dst[1] = (bf16)a.y; dst[2] = (bf16)a.z; dst[3] = (bf16)a.w;
        dst[4] = (bf16)b.x; dst[5] = (bf16)b.y; dst[6] = (bf16)b.z; dst[7] = (bf16)b.w;
    }
}

// ---------- pos embed (bilinear interp of 48x48 table) -> initializes bf16 x ----------
template <typename TI>
__global__ __launch_bounds__(256) void pos_embed_kernel(const int* __restrict__ flag,
                                                        const TI* __restrict__ tab,
                                                        bf16* __restrict__ x) {
    if (*flag != (sizeof(TI) == 4 ? 1 : 0)) return;
    int t = blockIdx.x;
    int row, col, gh, gw;
    tok_geo(t, row, col, gh, gw);
    float hi = row * 47.0f / (gh - 1);
    float wi = col * 47.0f / (gw - 1);
    int hf = (int)hi, wf = (int)wi;
    int hc = min(hf + 1, 47), wc = min(wf + 1, 47);
    float dh = hi - hf, dw = wi - wf;
    float w00 = (1.f - dh) * (1.f - dw);
    float w01 = (1.f - dh) * dw;
    float w10 = dh * (1.f - dw);
    float w11 = dh * dw;
    const TI* p00 = tab + (size_t)(hf * 48 + wf) * DMODEL;
    const TI* p01 = tab + (size_t)(hf * 48 + wc) * DMODEL;
    const TI* p10 = tab + (size_t)(hc * 48 + wf) * DMODEL;
    const TI* p11 = tab + (size_t)(hc * 48 + wc) * DMODEL;
    bf16* xr = x + (size_t)t * DMODEL;
    for (int d = threadIdx.x; d < DMODEL; d += 256)
        xr[d] = (bf16)(w00 * (float)p00[d] + w01 * (float)p01[d] +
                       w10 * (float)p10[d] + w11 * (float)p11[d]);
}

// ---------- LayerNorm: bf16 x row -> bf16 out ----------
template <typename TI>
__global__ __launch_bounds__(256) void ln_kernel(const int* __restrict__ flag,
                                                 const bf16* __restrict__ x,
                                                 const TI* __restrict__ s,
                                                 const TI* __restrict__ b,
                                                 bf16* __restrict__ out) {
    if (*flag != (sizeof(TI) == 4 ? 1 : 0)) return;
    const int row = blockIdx.x;
    const int tid = threadIdx.x;
    __shared__ float red[4];
    const bf16* xr = x + (size_t)row * DMODEL;
    float vals[5];
    int cnt = 0;
    float sum = 0.f;
    for (int i = tid; i < DMODEL; i += 256) { vals[cnt] = (float)xr[i]; sum += vals[cnt]; cnt++; }
#pragma unroll
    for (int off = 32; off > 0; off >>= 1) sum += __shfl_down(sum, off);
    if ((tid & 63) == 0) red[tid >> 6] = sum;
    __syncthreads();
    float mean = (red[0] + red[1] + red[2] + red[3]) * (1.0f / DMODEL);
    float vs = 0.f;
    for (int i = 0; i < cnt; i++) { float d = vals[i] - mean; vs += d * d; }
#pragma unroll
    for (int off = 32; off > 0; off >>= 1) vs += __shfl_down(vs, off);
    __syncthreads();
    if ((tid & 63) == 0) red[tid >> 6] = vs;
    __syncthreads();
    float var = (red[0] + red[1] + red[2] + red[3]) * (1.0f / DMODEL);
    float inv = rsqrtf(var + 1e-6f);
    int idx = 0;
    for (int i = tid; i < DMODEL; i += 256)
        out[(size_t)row * DMODEL + i] = (bf16)((vals[idx++] - mean) * inv * (float)s[i] + (float)b[i]);
}

// ---------- RoPE in-place on qkv[N,3,16,72]: thread owns pair (j, j+36) of q and k ----------
__global__ __launch_bounds__(256) void rope_inplace_kernel(bf16* __restrict__ qkv) {
    int idx = blockIdx.x * 256 + threadIdx.x;
    const int total = NTOK * 16 * 36;
    if (idx >= total) return;
    int j = idx % 36;
    int rest = idx / 36;
    int h = rest & 15;
    int t = rest >> 4;
    bf16* base = qkv + (size_t)t * 3456 + h * 72;
    int row, col, gh, gw;
    tok_geo(t, row, col, gh, gw);
    float pos = (float)((j < 18) ? row : col);
    int fi = (j < 18) ? j : j - 18;
    float ang = pos * powf(10000.0f, -(float)fi / 18.0f);
    float cv = cosf(ang), sv = sinf(ang);
    float q0v = (float)base[j],        q1v = (float)base[j + 36];
    float k0v = (float)base[1152 + j], k1v = (float)base[1152 + j + 36];
    base[j]          = (bf16)(q0v * cv - q1v * sv);
    base[j + 36]     = (bf16)(q1v * cv + q0v * sv);
    base[1152 + j]      = (bf16)(k0v * cv - k1v * sv);
    base[1152 + j + 36] = (bf16)(k1v * cv + k0v * sv);
}

// ---------- flash attention v4: round-2 staging (coalesced K map, kv-major V map, in-loop
// direct global->LDS) + Q-in-regs (no Qs buffer: 34KB LDS -> 4 blocks/CU) + no pre-PV
// barrier (Ps rows wave-private) + defer-max/exp2 softmax ----------
__global__ __launch_bounds__(256) void attn_kernel(const bf16* __restrict__ qkv,
                                                   bf16* __restrict__ outp) {
    const int bx = blockIdx.x;
    const int head = bx & 15;
    const int qt = bx >> 4;
    int sbase, slen, qtb;
    if (qt < 36)      { sbase = 0;    slen = 2304; qtb = 0;  }
    else if (qt < 68) { sbase = 2304; slen = 2048; qtb = 36; }
    else if (qt < 83) { sbase = 4352; slen = 960;  qtb = 68; }
    else              { sbase = 5312; slen = 960;  qtb = 83; }
    const int q0 = sbase + (qt - qtb) * 64;

    __shared__ bf16 Ks[64][104];  // stages Q once at entry, then K tiles
    __shared__ bf16 Vs[80][72];   // [feature][kv]
    __shared__ bf16 Ps[64][72];

    const int tid = threadIdx.x;
    const int wv = tid >> 6;
    const int lane = tid & 63;
    const int quad = lane >> 4;
    const int l15 = lane & 15;

    const size_t hoff = (size_t)head * 72;

    // zero pad Vs feature rows 72..79 (cols 0..63 are all PV reads) -- ONCE
    for (int c = tid; c < 64; c += 256) {
        int r = 72 + (c >> 3), cc = (c & 7) * 8;
        uint4 z = {0, 0, 0, 0};
        *(uint4*)&Vs[r][cc] = z;
    }

    // stage Q tile into Ks (zero-pad cols 72..95), hoist per-wave Q fragments to regs
    for (int c = tid; c < 768; c += 256) {
        int r = c / 12, cc = (c % 12) * 8;
        uint4 v = {0, 0, 0, 0};
        if (cc < 72) v = *(const uint4*)(qkv + (size_t)(q0 + r) * 3456 + hoff + cc);
        *(uint4*)&Ks[r][cc] = v;
    }
    __syncthreads();
    bf16x8 aq[3];
#pragma unroll
    for (int i = 0; i < 3; i++) aq[i] = *(const bf16x8*)&Ks[wv * 16 + l15][i * 32 + quad * 8];

    f32x4 o[5] = {};
    float m_i[4], l_i[4];
#pragma unroll
    for (int r = 0; r < 4; r++) { m_i[r] = -1e30f; l_i[r] = 0.f; }

    const float C1 = 0.17002234f;  // 72^-0.5 * log2(e)
    const int nkv = slen >> 6;
    for (int kt = 0; kt < nkv; kt++) {
        const int k0 = sbase + kt * 64;
        __syncthreads();  // barrier A: prior step's LDS reads (and entry aq hoist) done
        // stage K tile (coalesced r=c/12 map; zero-pad cols 72..95)
        for (int c = tid; c < 768; c += 256) {
            int r = c / 12, cc = (c % 12) * 8;
            uint4 v = {0, 0, 0, 0};
            if (cc < 72) v = *(const uint4*)(qkv + (size_t)(k0 + r) * 3456 + 1152 + hoff + cc);
            *(uint4*)&Ks[r][cc] = v;
        }
        // stage V transposed (kv-major map -> conflict-free scalar writes)
        for (int c = tid; c < 576; c += 256) {
            int r = c & 63, cc = (c >> 6) * 8;
            uint4 v = *(const uint4*)(qkv + (size_t)(k0 + r) * 3456 + 2304 + hoff + cc);
            const bf16* e = (const bf16*)&v;
#pragma unroll
            for (int i = 0; i < 8; i++) Vs[cc + i][r] = e[i];
        }
        __syncthreads();  // barrier B: tile staged

        // S = Q K^T (raw; scale folded into exp2 below)
        f32x4 sfr[4] = {};
#pragma unroll
        for (int kc = 0; kc < 3; kc++)
#pragma unroll
            for (int nt = 0; nt < 4; nt++) {
                bf16x8 bk = *(const bf16x8*)&Ks[nt * 16 + l15][kc * 32 + quad * 8];
                sfr[nt] = __builtin_amdgcn_mfma_f32_16x16x32_bf16(aq[kc], bk, sfr[nt], 0, 0, 0);
            }

        // online softmax; row = quad*4+reg, 16 lanes of the quad share a row
        float mx[4];
#pragma unroll
        for (int reg = 0; reg < 4; reg++) {
            float m = fmaxf(fmaxf(sfr[0][reg], sfr[1][reg]), fmaxf(sfr[2][reg], sfr[3][reg]));
            m = fmaxf(m, __shfl_xor(m, 1));
            m = fmaxf(m, __shfl_xor(m, 2));
            m = fmaxf(m, __shfl_xor(m, 4));
            m = fmaxf(m, __shfl_xor(m, 8));
            mx[reg] = m;
        }
        // defer-max: rescale only when some row max grew (wave-uniform branch)
        bool grow = (mx[0] > m_i[0]) || (mx[1] > m_i[1]) || (mx[2] > m_i[2]) || (mx[3] > m_i[3]);
        if (__any(grow)) {
#pragma unroll
            for (int reg = 0; reg < 4; reg++) {
                float mn = fmaxf(m_i[reg], mx[reg]);
                float a = __builtin_amdgcn_exp2f((m_i[reg] - mn) * C1);
                m_i[reg] = mn;
                l_i[reg] *= a;
#pragma unroll
                for (int nt = 0; nt < 5; nt++) o[nt][reg] *= a;
            }
        }
        float mc[4];
#pragma unroll
        for (int reg = 0; reg < 4; reg++) mc[reg] = m_i[reg] * C1;
        float rs[4] = {0.f, 0.f, 0.f, 0.f};
#pragma unroll
        for (int nt = 0; nt < 4; nt++)
#pragma unroll
            for (int reg = 0; reg < 4; reg++) {
                float p = __builtin_amdgcn_exp2f(fmaf(sfr[nt][reg], C1, -mc[reg]));
                sfr[nt][reg] = p;
                rs[reg] += p;
            }
#pragma unroll
        for (int reg = 0; reg < 4; reg++) {
            float r = rs[reg];
            r += __shfl_xor(r, 1);
            r += __shfl_xor(r, 2);
            r += __shfl_xor(r, 4);
            r += __shfl_xor(r, 8);
            l_i[reg] += r;
        }

        // P: C-layout -> LDS. Ps rows [wv*16, wv*16+16) are wave-private: no barrier needed;
        // compiler-inserted lgkmcnt orders the reads below.
#pragma unroll
        for (int nt = 0; nt < 4; nt++)
#pragma unroll
            for (int reg = 0; reg < 4; reg++)
                Ps[wv * 16 + quad * 4 + reg][nt * 16 + l15] = (bf16)sfr[nt][reg];

        // O += P @ V
#pragma unroll
        for (int kc = 0; kc < 2; kc++) {
            bf16x8 ap = *(const bf16x8*)&Ps[wv * 16 + l15][kc * 32 + quad * 8];
#pragma unroll
            for (int nt = 0; nt < 5; nt++) {
                bf16x8 bv = *(const bf16x8*)&Vs[nt * 16 + l15][kc * 32 + quad * 8];
                o[nt] = __builtin_amdgcn_mfma_f32_16x16x32_bf16(ap, bv, o[nt], 0, 0, 0);
            }
        }
    }

#pragma unroll
    for (int nt = 0; nt < 5; nt++)
#pragma unroll
        for (int reg = 0; reg < 4; reg++) {
            int c = nt * 16 + l15;
            if (c < 72) {
                int tok = q0 + wv * 16 + quad * 4 + reg;
                outp[(size_t)tok * DMODEL + head * 72 + c] = (bf16)(o[nt][reg] / l_i[reg]);
            }
        }
}

// ---------- OLD generic GEMM (fallback path when workspace too small) ----------
template <int MODE, typename TA, typename TB>
__global__ __launch_bounds__(256) void gemm_kernel(const int* __restrict__ flag,
                                                   const TA* __restrict__ A,
                                                   const TB* __restrict__ B,
                                                   const TB* __restrict__ bias,
                                                   void* __restrict__ outp,
                                                   int M, int N, int K) {
    if (*flag != (sizeof(TB) == 4 ? 1 : 0)) return;
    __shared__ bf16 As[128][40];
    __shared__ bf16 Bs[128][40];
    const int tid = threadIdx.x;
    const int m0 = blockIdx.y * 128;
    const int n0 = blockIdx.x * 128;
    const int wv = tid >> 6;
    const int lane = tid & 63;
    const int quad = lane >> 4;
    const int l15 = lane & 15;
    const int wr = (wv >> 1) * 64;
    const int wc = (wv & 1) * 64;

    const int a_row = tid >> 1;
    const int a_col = (tid & 1) * 16;
    const int b_k = tid & 31;
    const int b_n = (tid >> 5) * 16;

    f32x4 acc[4][4] = {};

    for (int k0 = 0; k0 < K; k0 += 32) {
        __syncthreads();
        {
            bf16 ea[16];
            int gr = m0 + a_row;
            const TA* ap = A + (size_t)gr * K + k0 + a_col;
            load8(ap, ea, gr < M && (k0 + a_col) < K);
            load8(ap + 8, ea + 8, gr < M && (k0 + a_col + 8) < K);
            *(uint4*)&As[a_row][a_col] = *(uint4*)ea;
            *(uint4*)&As[a_row][a_col + 8] = *(uint4*)(ea + 8);
        }
        {
            bf16 eb[16];
            int gk = k0 + b_k;
            const TB* bp = B + (size_t)gk * N + n0 + b_n;
            load8(bp, eb, gk < K && (n0 + b_n) < N);
            load8(bp + 8, eb + 8, gk < K && (n0 + b_n + 8) < N);
#pragma unroll
            for (int i = 0; i < 16; i++) Bs[b_n + i][b_k] = eb[i];
        }
        __syncthreads();

        bf16x8 af[4], bfv[4];
#pragma unroll
        for (int mi = 0; mi < 4; mi++) af[mi] = *(const bf16x8*)&As[wr + mi * 16 + l15][quad * 8];
#pragma unroll
        for (int ni = 0; ni < 4; ni++) bfv[ni] = *(const bf16x8*)&Bs[wc + ni * 16 + l15][quad * 8];
#pragma unroll
        for (int mi = 0; mi < 4; mi++)
#pragma unroll
            for (int ni = 0; ni < 4; ni++)
                acc[mi][ni] = __builtin_amdgcn_mfma_f32_16x16x32_bf16(af[mi], bfv[ni], acc[mi][ni], 0, 0, 0);
    }

#pragma unroll
    for (int mi = 0; mi < 4; mi++) {
#pragma unroll
        for (int ni = 0; ni < 4; ni++) {
#pragma unroll
            for (int reg = 0; reg < 4; reg++) {
                int r = m0 + wr + mi * 16 + quad * 4 + reg;
                int c = n0 + wc + ni * 16 + l15;
                if (r < M && c < N) {
                    float v = acc[mi][ni][reg] + (float)bias[c];
                    if (MODE == 1) v = gelu_tanh(v);
                    if (MODE == 2) {
                        bf16* o = (bf16*)outp;
                        size_t idx = (size_t)r * N + c;
                        o[idx] = (bf16)((float)o[idx] + v);
                    } else if (MODE == 3) {
                        TB* o = (TB*)outp;
                        o[(size_t)r * N + c] = (TB)v;
                    } else {
                        bf16* o = (bf16*)outp;
                        o[(size_t)r * N + c] = (bf16)v;
                    }
                }
            }
        }
    }
}

// ================= pre-transposed bf16 weights + global_load_lds GEMM =================

// flat dtype convert (pixels): n8 chunks of 8 elements
template <typename TI>
__global__ __launch_bounds__(256) void cvt_kernel(const int* __restrict__ flag,
                                                  const TI* __restrict__ in,
                                                  bf16* __restrict__ out, int n8) {
    if (*flag != (sizeof(TI) == 4 ? 1 : 0)) return;
    for (int i = blockIdx.x * 256 + threadIdx.x; i < n8; i += gridDim.x * 256) {
        bf16 e[8];
        load8(in + (size_t)i * 8, e, true);
        *(uint4*)(out + (size_t)i * 8) = *(uint4*)e;
    }
}

// transpose+convert weight: B[K][N] (TI) -> T[N][Kpad] (bf16), zero-padded k in [K,Kpad)
template <typename TI>
__global__ __launch_bounds__(256) void transpose_w_kernel(const int* __restrict__ flag,
                                                          const TI* __restrict__ B,
                                                          bf16* __restrict__ T,
                                                          int K, int N, int Kpad) {
    if (*flag != (sizeof(TI) == 4 ? 1 : 0)) return;
    __shared__ bf16 t[64][72];
    const int k0 = blockIdx.y * 64, n0 = blockIdx.x * 64;
    const int tid = threadIdx.x;
    const int kk = tid >> 2;
    const int nn0 = (tid & 3) * 16;
    bf16 e[16];
    bool ok = (k0 + kk < K) && (n0 + nn0 < N);  // N is a multiple of 16
    const TI* src = B + (size_t)(k0 + kk) * N + n0 + nn0;
    load8(src, e, ok);
    load8(src + 8, e + 8, ok);
#pragma unroll
    for (int i = 0; i < 16; i++) t[nn0 + i][kk] = e[i];
    __syncthreads();
    const int nn = tid >> 2;
    const int j16 = (tid & 3) * 16;
    if (n0 + nn < N && k0 + j16 < Kpad) {  // Kpad multiple of 32 -> full 16 fits
        bf16* dst = T + (size_t)(n0 + nn) * Kpad + k0 + j16;
        *(uint4*)dst = *(uint4*)&t[nn][j16];
        *(uint4*)(dst + 8) = *(uint4*)&t[nn][j16 + 8];
    }
}

// convert all 11 GEMM bias vectors into one bf16 arena
template <typename TI>
__global__ __launch_bounds__(256) void cvt_bias_kernel(const int* __restrict__ flag,
        const TI* p0, const TI* p1, const TI* p2, const TI* p3, const TI* p4,
        const TI* p5, const TI* p6, const TI* p7, const TI* p8, const TI* p9,
        const TI* p10, bf16* __restrict__ out) {
    if (*flag != (sizeof(TI) == 4 ? 1 : 0)) return;
    const int lens[11] = {1152, 3456, 3456, 1152, 1152, 4304, 4304, 1152, 1152, 4608, 2048};
    const int offs[11] = {0, 1152, 4608, 8064, 9216, 10368, 14672, 18976, 20128, 21280, 25888};
    int b = blockIdx.x;
    const TI* src = (b == 0) ? p0 : (b == 1) ? p1 : (b == 2) ? p2 : (b == 3) ? p3
                  : (b == 4) ? p4 : (b == 5) ? p5 : (b == 6) ? p6 : (b == 7) ? p7
                  : (b == 8) ? p8 : (b == 9) ? p9 : p10;
    for (int i = threadIdx.x; i < lens[b]; i += 256) out[offs[b] + i] = (bf16)(float)src[i];
}

typedef const __attribute__((address_space(1))) void* gas_ptr;
typedef __attribute__((address_space(3))) void* las_ptr;
__device__ __forceinline__ void gload16(const bf16* g, bf16* l) {
    __builtin_amdgcn_global_load_lds((gas_ptr)g, (las_ptr)l, 16, 0, 0);
}

// m97-style GEMM (BM=128): C[M,ldc] = A[M,K] @ BT[N,K]^T + bias.
// MODE 0: bf16 store; 1: bf16 gelu (zero-fills c in [N,ldc)); 2: bf16 +=; 3: store f32/bf16 by *flag
template <int MODE>
__global__ __launch_bounds__(256) void gemm_lds_kernel(const int* __restrict__ flag,
        const bf16* __restrict__ A, const bf16* __restrict__ BT,
        const bf16* __restrict__ bias, void* __restrict__ outp,
        int M, int N, int K, int ldc) {
    __shared__ bf16 As[128][32];
    __shared__ bf16 Bs[128][32];
    const int tid = threadIdx.x;
    const int m0 = blockIdx.y * 128;
    const int n0 = blockIdx.x * 128;
    const int wv = tid >> 6;
    const int lane = tid & 63;
    const int quad = lane >> 4;
    const int l15 = lane & 15;
    const int wr = (wv >> 1) * 64;
    const int wc = (wv & 1) * 64;

    const int sr = wv * 32 + (lane >> 2);
    const int sc = (lane & 3) * 8;
    const bf16* aP0 = A + (size_t)min(m0 + sr, M - 1) * K + sc;
    const bf16* aP1 = A + (size_t)min(m0 + sr + 16, M - 1) * K + sc;
    const bf16* bP0 = BT + (size_t)min(n0 + sr, N - 1) * K + sc;
    const bf16* bP1 = BT + (size_t)min(n0 + sr + 16, N - 1) * K + sc;
    bf16* lA0 = &As[wv * 32][0];
    bf16* lA1 = &As[wv * 32 + 16][0];
    bf16* lB0 = &Bs[wv * 32][0];
    bf16* lB1 = &Bs[wv * 32 + 16][0];

    f32x4 acc[4][4] = {};
    for (int k0 = 0; k0 < K; k0 += 32) {
        __syncthreads();
        gload16(aP0 + k0, lA0);
        gload16(aP1 + k0, lA1);
        gload16(bP0 + k0, lB0);
        gload16(bP1 + k0, lB1);
        __syncthreads();
        bf16x8 af[4], bfv[4];
#pragma unroll
        for (int mi = 0; mi < 4; mi++) af[mi] = *(const bf16x8*)&As[wr + mi * 16 + l15][quad * 8];
#pragma unroll
        for (int ni = 0; ni < 4; ni++) bfv[ni] = *(const bf16x8*)&Bs[wc + ni * 16 + l15][quad * 8];
#pragma unroll
        for (int mi = 0; mi < 4; mi++)
#pragma unroll
            for (int ni = 0; ni < 4; ni++)
                acc[mi][ni] = __builtin_amdgcn_mfma_f32_16x16x32_bf16(af[mi], bfv[ni], acc[mi][ni], 0, 0, 0);
    }

    const int isf32 = (MODE == 3) ? *flag : 0;
#pragma unroll
    for (int mi = 0; mi < 4; mi++) {
#pragma unroll
        for (int ni = 0; ni < 4; ni++) {
#pragma unroll
            for (int reg = 0; reg < 4; reg++) {
                int r = m0 + wr + mi * 16 + quad * 4 + reg;
                int c = n0 + wc + ni * 16 + l15;
                if (r < M && c < ldc) {
                    float v = 0.f;
                    if (c < N) {
                        v = acc[mi][ni][reg] + (float)bias[c];
                        if (MODE == 1) v = gelu_tanh(v);
                    }
                    if (MODE == 2) {
                        bf16* o = (bf16*)outp;
                        size_t idx = (size_t)r * ldc + c;
                        o[idx] = (bf16)((float)o[idx] + v);
                    } else if (MODE == 3) {
                        if (isf32) ((float*)outp)[(size_t)r * ldc + c] = v;
                        else       ((bf16*)outp)[(size_t)r * ldc + c] = (bf16)v;
                    } else {
                        ((bf16*)outp)[(size_t)r * ldc + c] = (bf16)v;
                    }
                }
            }
        }
    }
}

// BM=64 variant for grid-starved GEMMs (N small -> few 128x128 blocks). Same inner pattern:
// 3 global_load_lds/wave, 8 MFMA/wave/k-step, 2x the blocks of the 128 variant.
template <int MODE>
__global__ __launch_bounds__(256) void gemm_lds64_kernel(const int* __restrict__ flag,
        const bf16* __restrict__ A, const bf16* __restrict__ BT,
        const bf16* __restrict__ bias, void* __restrict__ outp,
        int M, int N, int K, int ldc) {
    __shared__ bf16 As[64][32];
    __shared__ bf16 Bs[128][32];
    const int tid = threadIdx.x;
    const int m0 = blockIdx.y * 64;
    const int n0 = blockIdx.x * 128;
    const int wv = tid >> 6;
    const int lane = tid & 63;
    const int quad = lane >> 4;
    const int l15 = lane & 15;
    const int wr = (wv >> 1) * 32;
    const int wc = (wv & 1) * 64;

    const int sc = (lane & 3) * 8;
    const int srA = wv * 16 + (lane >> 2);
    const int srB = wv * 32 + (lane >> 2);
    const bf16* aP0 = A + (size_t)min(m0 + srA, M - 1) * K + sc;
    const bf16* bP0 = BT + (size_t)min(n0 + srB, N - 1) * K + sc;
    const bf16* bP1 = BT + (size_t)min(n0 + srB + 16, N - 1) * K + sc;
    bf16* lA0 = &As[wv * 16][0];
    bf16* lB0 = &Bs[wv * 32][0];
    bf16* lB1 = &Bs[wv * 32 + 16][0];

    f32x4 acc[2][4] = {};
    for (int k0 = 0; k0 < K; k0 += 32) {
        __syncthreads();
        gload16(aP0 + k0, lA0);
        gload16(bP0 + k0, lB0);
        gload16(bP1 + k0, lB1);
        __syncthreads();
        bf16x8 af[2], bfv[4];
#pragma unroll
        for (int mi = 0; mi < 2; mi++) af[mi] = *(const bf16x8*)&As[wr + mi * 16 + l15][quad * 8];
#pragma unroll
        for (int ni = 0; ni < 4; ni++) bfv[ni] = *(const bf16x8*)&Bs[wc + ni * 16 + l15][quad * 8];
#pragma unroll
        for (int mi = 0; mi < 2; mi++)
#pragma unroll
            for (int ni = 0; ni < 4; ni++)
                acc[mi][ni] = __builtin_amdgcn_mfma_f32_16x16x32_bf16(af[mi], bfv[ni], acc[mi][ni], 0, 0, 0);
    }

    const int isf32 = (MODE == 3) ? *flag : 0;
#pragma unroll
    for (int mi = 0; mi < 2; mi++) {
#pragma unroll
        for (int ni = 0; ni < 4; ni++) {
#pragma unroll
            for (int reg = 0; reg < 4; reg++) {
                int r = m0 + wr + mi * 16 + quad * 4 + reg;
                int c = n0 + wc + ni * 16 + l15;
                if (r < M && c < ldc) {
                    float v = 0.f;
                    if (c < N) {
                        v = acc[mi][ni][reg] + (float)bias[c];
                        if (MODE == 1) v = gelu_tanh(v);
                    }
                    if (MODE == 2) {
                        bf16* o = (bf16*)outp;
                        size_t idx = (size_t)r * ldc + c;
                        o[idx] = (bf16)((float)o[idx] + v);
                    } else if (MODE == 3) {
                        if (isf32) ((float*)outp)[(size_t)r * ldc + c] = v;
                        else       ((bf16*)outp)[(size_t)r * ldc + c] = (bf16)v;
                    } else {
                        ((bf16*)outp)[(size_t)r * ldc + c] = (bf16)v;
                    }
                }
            }
        }
    }
}

// ---------- arena layout (bf16 elements) ----------
#define OFF_PATCH  0ULL
#define OFF_QKV    1769472ULL
#define QKV_SZ     3981312ULL
#define OFF_PROJ   9732096ULL
#define PROJ_SZ    1327104ULL
#define OFF_FC1    12386304ULL
#define FC1_SZ     4958208ULL
#define OFF_FC2    22302720ULL
#define FC2_SZ     4976640ULL
#define OFF_MFC1   32256000ULL
#define OFF_MFC2   53489664ULL
#define OFF_BIAS   62926848ULL
#define WS_NEEDED  209001280ULL

extern "C" void kernel_launch(void* const* d_in, const int* in_sizes, int n_in,
                              void* d_out, int out_size, void* d_ws, size_t ws_size,
                              hipStream_t stream) {
    char* ws = (char*)d_ws;
    int* flag  = (int*)ws;                       // 256 B reserved
    bf16* x    = (bf16*)(ws + 256);              // 14,450,688 B
    bf16* h    = (bf16*)(ws + 256 + 14450688);   // 14,450,688 B
    bf16* bufA = (bf16*)(ws + 256 + 28901376);   // 54,190,080 B (6272*4320*2)

    detect_kernel<<<1, 64, 0, stream>>>((const unsigned short*)d_in[0], flag);

    if (ws_size >= WS_NEEDED) {
        // ---------------- NEW PATH ----------------
        bf16* wT = (bf16*)(ws + 256 + 28901376 + 54190080);
        bf16* bias = wT + OFF_BIAS;
        bf16* px = bufA;  // pixels-as-bf16 live in bufA until the patch GEMM is done

        // pixel convert (6272*1536 / 8 = 1,204,224 chunks)
        cvt_kernel<bf16><<<1024, 256, 0, stream>>>(flag, (const bf16*)d_in[0], px, 1204224);
        cvt_kernel<float><<<1024, 256, 0, stream>>>(flag, (const float*)d_in[0], px, 1204224);

        // weight transposes (both dtype instantiations; only the matching one runs)
        auto T2 = [&](const void* srcBase, size_t eoff, bf16* dst, int K, int N, int Kpad) {
            dim3 g((N + 63) / 64, (Kpad + 63) / 64);
            transpose_w_kernel<bf16><<<g, 256, 0, stream>>>(flag, (const bf16*)srcBase + eoff, dst, K, N, Kpad);
            transpose_w_kernel<float><<<g, 256, 0, stream>>>(flag, (const float*)srcBase + eoff, dst, K, N, Kpad);
        };
        T2(d_in[2], 0, wT + OFF_PATCH, 1536, 1152, 1536);
        for (int l = 0; l < 2; l++) {
            T2(d_in[7],  (size_t)l * 1152 * 3456, wT + OFF_QKV + l * QKV_SZ, 1152, 3456, 1152);
            T2(d_in[9],  (size_t)l * 1152 * 1152, wT + OFF_PROJ + l * PROJ_SZ, 1152, 1152, 1152);
            T2(d_in[13], (size_t)l * 1152 * 4304, wT + OFF_FC1 + l * FC1_SZ, 1152, 4304, 1152);
            T2(d_in[15], (size_t)l * 4304 * 1152, wT + OFF_FC2 + l * FC2_SZ, 4304, 1152, 4320);
        }
        T2(d_in[19], 0, wT + OFF_MFC1, 4608, 4608, 4608);
        T2(d_in[21], 0, wT + OFF_MFC2, 4608, 2048, 4608);

        cvt_bias_kernel<bf16><<<11, 256, 0, stream>>>(flag,
            (const bf16*)d_in[3],
            (const bf16*)d_in[8], (const bf16*)d_in[8] + 3456,
            (const bf16*)d_in[10], (const bf16*)d_in[10] + 1152,
            (const bf16*)d_in[14], (const bf16*)d_in[14] + 4304,
            (const bf16*)d_in[16], (const bf16*)d_in[16] + 1152,
            (const bf16*)d_in[20], (const bf16*)d_in[22], bias);
        cvt_bias_kernel<float><<<11, 256, 0, stream>>>(flag,
            (const float*)d_in[3],
            (const float*)d_in[8], (const float*)d_in[8] + 3456,
            (const float*)d_in[10], (const float*)d_in[10] + 1152,
            (const float*)d_in[14], (const float*)d_in[14] + 4304,
            (const float*)d_in[16], (const float*)d_in[16] + 1152,
            (const float*)d_in[20], (const float*)d_in[22], bias);

        pos_embed_kernel<bf16><<<NTOK, 256, 0, stream>>>(flag, (const bf16*)d_in[4], x);
        pos_embed_kernel<float><<<NTOK, 256, 0, stream>>>(flag, (const float*)d_in[4], x);

        gemm_lds64_kernel<2><<<dim3(9, 98), 256, 0, stream>>>(flag, px, wT + OFF_PATCH,
                                                              bias + 0, x, NTOK, 1152, 1536, 1152);

        for (int l = 0; l < 2; l++) {
            ln_kernel<bf16><<<NTOK, 256, 0, stream>>>(flag, x, (const bf16*)d_in[5] + l * 1152,
                                                      (const bf16*)d_in[6] + l * 1152, h);
            ln_kernel<float><<<NTOK, 256, 0, stream>>>(flag, x, (const float*)d_in[5] + l * 1152,
                                                       (const float*)d_in[6] + l * 1152, h);
            gemm_lds_kernel<0><<<dim3(27, 49), 256, 0, stream>>>(flag, h, wT + OFF_QKV + l * QKV_SZ,
                                                                 bias + 1152 + l * 3456, bufA,
                                                                 NTOK, 3456, 1152, 3456);
            rope_inplace_kernel<<<(NTOK * 16 * 36 + 255) / 256, 256, 0, stream>>>(bufA);
            attn_kernel<<<98 * 16, 256, 0, stream>>>(bufA, h);
            gemm_lds64_kernel<2><<<dim3(9, 98), 256, 0, stream>>>(flag, h, wT + OFF_PROJ + l * PROJ_SZ,
                                                                  bias + 8064 + l * 1152, x,
                                                                  NTOK, 1152, 1152, 1152);
            ln_kernel<bf16><<<NTOK, 256, 0, stream>>>(flag, x, (const bf16*)d_in[11] + l * 1152,
                                                      (const bf16*)d_in[12] + l * 1152, h);
            ln_kernel<float><<<NTOK, 256, 0, stream>>>(flag, x, (const float*)d_in[11] + l * 1152,
                                                       (const float*)d_in[12] + l * 1152, h);
            // fc1: ldc=4320, zero-fills pad cols so fc2 can run K=4320
            gemm_lds_kernel<1><<<dim3(34, 49), 256, 0, stream>>>(flag, h, wT + OFF_FC1 + l * FC1_SZ,
                                                                 bias + 10368 + l * 4304, bufA,
                                                                 NTOK, 4304, 1152, 4320);
            gemm_lds64_kernel<2><<<dim3(9, 98), 256, 0, stream>>>(flag, bufA, wT + OFF_FC2 + l * FC2_SZ,
                                                                  bias + 18976 + l * 1152, x,
                                                                  NTOK, 1152, 4320, 1152);
        }
        ln_kernel<bf16><<<NTOK, 256, 0, stream>>>(flag, x, (const bf16*)d_in[17], (const bf16*)d_in[18], h);
        ln_kernel<float><<<NTOK, 256, 0, stream>>>(flag, x, (const float*)d_in[17], (const float*)d_in[18], h);
        gemm_lds_kernel<1><<<dim3(36, 13), 256, 0, stream>>>(flag, h, wT + OFF_MFC1,
                                                             bias + 21280, bufA, 1568, 4608, 4608, 4608);
        gemm_lds64_kernel<3><<<dim3(16, 25), 256, 0, stream>>>(flag, bufA, wT + OFF_MFC2,
                                                               bias + 25888, d_out, 1568, 2048, 4608, 2048);
        return;
    }

    // ---------------- FALLBACK: round-1 verified path ----------------
    {
        pos_embed_kernel<bf16><<<NTOK, 256, 0, stream>>>(flag, (const bf16*)d_in[4], x);
        pos_embed_kernel<float><<<NTOK, 256, 0, stream>>>(flag, (const float*)d_in[4], x);
        gemm_kernel<2, bf16, bf16><<<dim3(9, 49), 256, 0, stream>>>(
            flag, (const bf16*)d_in[0], (const bf16*)d_in[2], (const bf16*)d_in[3], x, NTOK, 1152, 1536);
        gemm_kernel<2, float, float><<<dim3(9, 49), 256, 0, stream>>>(
            flag, (const float*)d_in[0], (const float*)d_in[2], (const float*)d_in[3], x, NTOK, 1152, 1536);
    }
    for (int l = 0; l < 2; l++) {
        ln_kernel<bf16><<<NTOK, 256, 0, stream>>>(flag, x, (const bf16*)d_in[5] + l * 1152,
                                                  (const bf16*)d_in[6] + l * 1152, h);
        ln_kernel<float><<<NTOK, 256, 0, stream>>>(flag, x, (const float*)d_in[5] + l * 1152,
                                                   (const float*)d_in[6] + l * 1152, h);
        gemm_kernel<0, bf16, bf16><<<dim3(27, 49), 256, 0, stream>>>(
            flag, h, (const bf16*)d_in[7] + (size_t)l * 1152 * 3456,
            (const bf16*)d_in[8] + l * 3456, bufA, NTOK, 3456, 1152);
        gemm_kernel<0, bf16, float><<<dim3(27, 49), 256, 0, stream>>>(
            flag, h, (const float*)d_in[7] + (size_t)l * 1152 * 3456,
            (const float*)d_in[8] + l * 3456, bufA, NTOK, 3456, 1152);
        rope_inplace_kernel<<<(NTOK * 16 * 36 + 255) / 256, 256, 0, stream>>>(bufA);
        attn_kernel<<<98 * 16, 256, 0, stream>>>(bufA, h);
        gemm_kernel<2, bf16, bf16><<<dim3(9, 49), 256, 0, stream>>>(
            flag, h, (const bf16*)d_in[9] + (size_t)l * 1152 * 1152,
            (const bf16*)d_in[10] + l * 1152, x, NTOK, 1152, 1152);
        gemm_kernel<2, bf16, float><<<dim3(9, 49), 256, 0, stream>>>(
            flag, h, (const float*)d_in[9] + (size_t)l * 1152 * 1152,
            (const float*)d_in[10] + l * 1152, x, NTOK, 1152, 1152);
        ln_kernel<bf16><<<NTOK, 256, 0, stream>>>(flag, x, (const bf16*)d_in[11] + l * 1152,
                                                  (const bf16*)d_in[12] + l * 1152, h);
        ln_kernel<float><<<NTOK, 256, 0, stream>>>(flag, x, (const float*)d_in[11] + l * 1152,
                                                   (const float*)d_in[12] + l * 1152, h);
        gemm_kernel<1, bf16, bf16><<<dim3(34, 49), 256, 0, stream>>>(
            flag, h, (const bf16*)d_in[13] + (size_t)l * 1152 * 4304,
            (const bf16*)d_in[14] + l * 4304, bufA, NTOK, 4304, 1152);
        gemm_kernel<1, bf16, float><<<dim3(34, 49), 256, 0, stream>>>(
            flag, h, (const float*)d_in[13] + (size_t)l * 1152 * 4304,
            (const float*)d_in[14] + l * 4304, bufA, NTOK, 4304, 1152);
        gemm_kernel<2, bf16, bf16><<<dim3(9, 49), 256, 0, stream>>>(
            flag, bufA, (const bf16*)d_in[15] + (size_t)l * 4304 * 1152,
            (const bf16*)d_in[16] + l * 1152, x, NTOK, 1152, 4304);
        gemm_kernel<2, bf16, float><<<dim3(9, 49), 256, 0, stream>>>(
            flag, bufA, (const float*)d_in[15] + (size_t)l * 4304 * 1152,
            (const float*)d_in[16] + l * 1152, x, NTOK, 1152, 4304);
    }
    ln_kernel<bf16><<<NTOK, 256, 0, stream>>>(flag, x, (const bf16*)d_in[17], (const bf16*)d_in[18], h);
    ln_kernel<float><<<NTOK, 256, 0, stream>>>(flag, x, (const float*)d_in[17], (const float*)d_in[18], h);
    gemm_kernel<1, bf16, bf16><<<dim3(36, 13), 256, 0, stream>>>(
        flag, h, (const bf16*)d_in[19], (const bf16*)d_in[20], bufA, 1568, 4608, 4608);
    gemm_kernel<1, bf16, float><<<dim3(36, 13), 256, 0, stream>>>(
        flag, h, (const float*)d_in[19], (const float*)d_in[20], bufA, 1568, 4608, 4608);
    gemm_kernel<3, bf16, bf16><<<dim3(16, 13), 256, 0, stream>>>(
        flag, bufA, (const bf16*)d_in[21], (const bf16*)d_in[22], d_out, 1568, 2048, 4608);
    gemm_kernel<3, bf16, float><<<dim3(16, 13), 256, 0, stream>>>(
        flag, bufA, (const float*)d_in[21], (const float*)d_in[22], d_out, 1568, 2048, 4608);
}

// Round 6
// 2167.388 us; speedup vs baseline: 1.0896x; 1.0204x over previous
//
#include <hip/hip_runtime.h>

typedef __bf16 bf16;
typedef float f32x4 __attribute__((ext_vector_type(4)));
typedef bf16 bf16x8 __attribute__((ext_vector_type(8)));

#define NTOK 6272
#define DMODEL 1152

// ---------- per-token geometry (GRID = [[1,48,48],[1,32,64],[2,24,40]]) ----------
__device__ __forceinline__ void tok_geo(int t, int& row, int& col, int& gh, int& gw) {
    int local;
    if (t < 2304)      { local = t;        gh = 48; gw = 48; }
    else if (t < 4352) { local = t - 2304; gh = 32; gw = 64; }
    else if (t < 5312) { local = t - 4352; gh = 24; gw = 40; }
    else               { local = t - 5312; gh = 24; gw = 40; }
    int mc = local & 1;
    int mr = (local >> 1) & 1;
    int rest = local >> 2;
    int mwc = gw >> 1;
    int mw = rest % mwc;
    int mh = rest / mwc;
    row = mh * 2 + mr;
    col = mw * 2 + mc;
}

__device__ __forceinline__ float gelu_tanh(float v) {
    float c = v + 0.044715f * v * v * v;
    return 0.5f * v * (1.0f + tanhf(0.7978845608028654f * c));
}

// ---------- runtime dtype detection: fp32 mantissa halves have wild bf16 exponents ----------
__global__ void detect_kernel(const unsigned short* __restrict__ px, int* __restrict__ flag) {
    int tid = threadIdx.x; // 64 threads
    int cnt = 0;
    for (int i = tid * 8; i < tid * 8 + 8; i++) {
        unsigned e = (px[i] >> 7) & 0xFF;
        if (e < 100u || e > 140u) cnt++;
    }
#pragma unroll
    for (int off = 32; off > 0; off >>= 1) cnt += __shfl_down(cnt, off);
    if (tid == 0) *flag = (cnt > 64) ? 1 : 0;  // 1 = inputs are fp32
}

// load 8 elements (any float type) -> 8 bf16 in regs; zero-fill if !pred
template <typename T>
__device__ __forceinline__ void load8(const T* src, bf16* dst, bool pred) {
    if (!pred) {
        uint4 z = {0, 0, 0, 0};
        *(uint4*)dst = z;
        return;
    }
    if constexpr (sizeof(T) == 2) {
        *(uint4*)dst = *(const uint4*)src;
    } else {
        float4 a = *(const float4*)src;
        float4 b = *(const float4*)(src + 4);
        dst[0] = (bf16)a.x; dst[1] = (bf16)a.y; dst[2] = (bf16)a.z; dst[3] = (bf16)a.w;
        dst[4] = (bf16)b.x; dst[5] = (bf16)b.y; dst[6] = (bf16)b.z; dst[7] = (bf16)b.w;
    }
}

// ================= fused-dtype kernels (single launch, runtime *flag branch) =================

// pos embed (bilinear interp of 48x48 table) -> initializes bf16 x
__global__ __launch_bounds__(256) void pos_embed2_kernel(const int* __restrict__ flag,
                                                         const bf16* __restrict__ tab16,
                                                         const float* __restrict__ tab32,
                                                         bf16* __restrict__ x) {
    const bool f32 = (*flag != 0);
    int t = blockIdx.x;
    int row, col, gh, gw;
    tok_geo(t, row, col, gh, gw);
    float hi = row * 47.0f / (gh - 1);
    float wi = col * 47.0f / (gw - 1);
    int hf = (int)hi, wf = (int)wi;
    int hc = min(hf + 1, 47), wc = min(wf + 1, 47);
    float dh = hi - hf, dw = wi - wf;
    float w00 = (1.f - dh) * (1.f - dw);
    float w01 = (1.f - dh) * dw;
    float w10 = dh * (1.f - dw);
    float w11 = dh * dw;
    size_t i00 = (size_t)(hf * 48 + wf) * DMODEL;
    size_t i01 = (size_t)(hf * 48 + wc) * DMODEL;
    size_t i10 = (size_t)(hc * 48 + wf) * DMODEL;
    size_t i11 = (size_t)(hc * 48 + wc) * DMODEL;
    bf16* xr = x + (size_t)t * DMODEL;
    if (f32) {
        for (int d = threadIdx.x; d < DMODEL; d += 256)
            xr[d] = (bf16)(w00 * tab32[i00 + d] + w01 * tab32[i01 + d] +
                           w10 * tab32[i10 + d] + w11 * tab32[i11 + d]);
    } else {
        for (int d = threadIdx.x; d < DMODEL; d += 256)
            xr[d] = (bf16)(w00 * (float)tab16[i00 + d] + w01 * (float)tab16[i01 + d] +
                           w10 * (float)tab16[i10 + d] + w11 * (float)tab16[i11 + d]);
    }
}

// LayerNorm: bf16 x row -> bf16 out (scale/bias in either dtype)
__global__ __launch_bounds__(256) void ln2_kernel(const int* __restrict__ flag,
                                                  const bf16* __restrict__ x,
                                                  const bf16* __restrict__ s16,
                                                  const bf16* __restrict__ b16,
                                                  const float* __restrict__ s32,
                                                  const float* __restrict__ b32,
                                                  bf16* __restrict__ out) {
    const bool f32 = (*flag != 0);
    const int row = blockIdx.x;
    const int tid = threadIdx.x;
    __shared__ float red[4];
    const bf16* xr = x + (size_t)row * DMODEL;
    float vals[5];
    int cnt = 0;
    float sum = 0.f;
    for (int i = tid; i < DMODEL; i += 256) { vals[cnt] = (float)xr[i]; sum += vals[cnt]; cnt++; }
#pragma unroll
    for (int off = 32; off > 0; off >>= 1) sum += __shfl_down(sum, off);
    if ((tid & 63) == 0) red[tid >> 6] = sum;
    __syncthreads();
    float mean = (red[0] + red[1] + red[2] + red[3]) * (1.0f / DMODEL);
    float vs = 0.f;
    for (int i = 0; i < cnt; i++) { float d = vals[i] - mean; vs += d * d; }
#pragma unroll
    for (int off = 32; off > 0; off >>= 1) vs += __shfl_down(vs, off);
    __syncthreads();
    if ((tid & 63) == 0) red[tid >> 6] = vs;
    __syncthreads();
    float var = (red[0] + red[1] + red[2] + red[3]) * (1.0f / DMODEL);
    float inv = rsqrtf(var + 1e-6f);
    int idx = 0;
    for (int i = tid; i < DMODEL; i += 256) {
        float sv = f32 ? s32[i] : (float)s16[i];
        float bv = f32 ? b32[i] : (float)b16[i];
        out[(size_t)row * DMODEL + i] = (bf16)((vals[idx++] - mean) * inv * sv + bv);
    }
}

// flat dtype convert (pixels): n8 chunks of 8 elements
__global__ __launch_bounds__(256) void cvt2_kernel(const int* __restrict__ flag,
                                                   const bf16* __restrict__ in16,
                                                   const float* __restrict__ in32,
                                                   bf16* __restrict__ out, int n8) {
    const bool f32 = (*flag != 0);
    for (int i = blockIdx.x * 256 + threadIdx.x; i < n8; i += gridDim.x * 256) {
        bf16 e[8];
        if (f32) load8(in32 + (size_t)i * 8, e, true);
        else     load8(in16 + (size_t)i * 8, e, true);
        *(uint4*)(out + (size_t)i * 8) = *(uint4*)e;
    }
}

// transpose+convert weight: B[K][N] -> T[N][Kpad] (bf16), zero-padded k in [K,Kpad)
__global__ __launch_bounds__(256) void transpose_w2_kernel(const int* __restrict__ flag,
                                                           const bf16* __restrict__ B16,
                                                           const float* __restrict__ B32,
                                                           bf16* __restrict__ T,
                                                           int K, int N, int Kpad) {
    const bool f32 = (*flag != 0);
    __shared__ bf16 t[64][72];
    const int k0 = blockIdx.y * 64, n0 = blockIdx.x * 64;
    const int tid = threadIdx.x;
    const int kk = tid >> 2;
    const int nn0 = (tid & 3) * 16;
    bf16 e[16];
    bool ok = (k0 + kk < K) && (n0 + nn0 < N);  // N is a multiple of 16
    size_t idx = (size_t)(k0 + kk) * N + n0 + nn0;
    if (f32) { load8(B32 + idx, e, ok); load8(B32 + idx + 8, e + 8, ok); }
    else     { load8(B16 + idx, e, ok); load8(B16 + idx + 8, e + 8, ok); }
#pragma unroll
    for (int i = 0; i < 16; i++) t[nn0 + i][kk] = e[i];
    __syncthreads();
    const int nn = tid >> 2;
    const int j16 = (tid & 3) * 16;
    if (n0 + nn < N && k0 + j16 < Kpad) {  // Kpad multiple of 32 -> full 16 fits
        bf16* dst = T + (size_t)(n0 + nn) * Kpad + k0 + j16;
        *(uint4*)dst = *(uint4*)&t[nn][j16];
        *(uint4*)(dst + 8) = *(uint4*)&t[nn][j16 + 8];
    }
}

// convert all 11 GEMM bias vectors into one bf16 arena (tiny grid; dual-launch kept)
template <typename TI>
__global__ __launch_bounds__(256) void cvt_bias_kernel(const int* __restrict__ flag,
        const TI* p0, const TI* p1, const TI* p2, const TI* p3, const TI* p4,
        const TI* p5, const TI* p6, const TI* p7, const TI* p8, const TI* p9,
        const TI* p10, bf16* __restrict__ out) {
    if (*flag != (sizeof(TI) == 4 ? 1 : 0)) return;
    const int lens[11] = {1152, 3456, 3456, 1152, 1152, 4304, 4304, 1152, 1152, 4608, 2048};
    const int offs[11] = {0, 1152, 4608, 8064, 9216, 10368, 14672, 18976, 20128, 21280, 25888};
    int b = blockIdx.x;
    const TI* src = (b == 0) ? p0 : (b == 1) ? p1 : (b == 2) ? p2 : (b == 3) ? p3
                  : (b == 4) ? p4 : (b == 5) ? p5 : (b == 6) ? p6 : (b == 7) ? p7
                  : (b == 8) ? p8 : (b == 9) ? p9 : p10;
    for (int i = threadIdx.x; i < lens[b]; i += 256) out[offs[b] + i] = (bf16)(float)src[i];
}

// ---------- RoPE in-place on qkv[N,3,16,72]: thread owns pair (j, j+36) of q and k ----------
__global__ __launch_bounds__(256) void rope_inplace_kernel(bf16* __restrict__ qkv) {
    int idx = blockIdx.x * 256 + threadIdx.x;
    const int total = NTOK * 16 * 36;
    if (idx >= total) return;
    int j = idx % 36;
    int rest = idx / 36;
    int h = rest & 15;
    int t = rest >> 4;
    bf16* base = qkv + (size_t)t * 3456 + h * 72;
    int row, col, gh, gw;
    tok_geo(t, row, col, gh, gw);
    float pos = (float)((j < 18) ? row : col);
    int fi = (j < 18) ? j : j - 18;
    float ang = pos * powf(10000.0f, -(float)fi / 18.0f);
    float cv = cosf(ang), sv = sinf(ang);
    float q0v = (float)base[j],        q1v = (float)base[j + 36];
    float k0v = (float)base[1152 + j], k1v = (float)base[1152 + j + 36];
    base[j]          = (bf16)(q0v * cv - q1v * sv);
    base[j + 36]     = (bf16)(q1v * cv + q0v * sv);
    base[1152 + j]      = (bf16)(k0v * cv - k1v * sv);
    base[1152 + j + 36] = (bf16)(k1v * cv + k0v * sv);
}

// ---------- flash attention v5: v4 + s_setprio around MFMA clusters ----------
__global__ __launch_bounds__(256) void attn_kernel(const bf16* __restrict__ qkv,
                                                   bf16* __restrict__ outp) {
    const int bx = blockIdx.x;
    const int head = bx & 15;
    const int qt = bx >> 4;
    int sbase, slen, qtb;
    if (qt < 36)      { sbase = 0;    slen = 2304; qtb = 0;  }
    else if (qt < 68) { sbase = 2304; slen = 2048; qtb = 36; }
    else if (qt < 83) { sbase = 4352; slen = 960;  qtb = 68; }
    else              { sbase = 5312; slen = 960;  qtb = 83; }
    const int q0 = sbase + (qt - qtb) * 64;

    __shared__ bf16 Ks[64][104];  // stages Q once at entry, then K tiles
    __shared__ bf16 Vs[80][72];   // [feature][kv]
    __shared__ bf16 Ps[64][72];

    const int tid = threadIdx.x;
    const int wv = tid >> 6;
    const int lane = tid & 63;
    const int quad = lane >> 4;
    const int l15 = lane & 15;

    const size_t hoff = (size_t)head * 72;

    // zero pad Vs feature rows 72..79 (cols 0..63 are all PV reads) -- ONCE
    for (int c = tid; c < 64; c += 256) {
        int r = 72 + (c >> 3), cc = (c & 7) * 8;
        uint4 z = {0, 0, 0, 0};
        *(uint4*)&Vs[r][cc] = z;
    }

    // stage Q tile into Ks (zero-pad cols 72..95), hoist per-wave Q fragments to regs
    for (int c = tid; c < 768; c += 256) {
        int r = c / 12, cc = (c % 12) * 8;
        uint4 v = {0, 0, 0, 0};
        if (cc < 72) v = *(const uint4*)(qkv + (size_t)(q0 + r) * 3456 + hoff + cc);
        *(uint4*)&Ks[r][cc] = v;
    }
    __syncthreads();
    bf16x8 aq[3];
#pragma unroll
    for (int i = 0; i < 3; i++) aq[i] = *(const bf16x8*)&Ks[wv * 16 + l15][i * 32 + quad * 8];

    f32x4 o[5] = {};
    float m_i[4], l_i[4];
#pragma unroll
    for (int r = 0; r < 4; r++) { m_i[r] = -1e30f; l_i[r] = 0.f; }

    const float C1 = 0.17002234f;  // 72^-0.5 * log2(e)
    const int nkv = slen >> 6;
    for (int kt = 0; kt < nkv; kt++) {
        const int k0 = sbase + kt * 64;
        __syncthreads();  // barrier A: prior step's LDS reads (and entry aq hoist) done
        // stage K tile (coalesced r=c/12 map; zero-pad cols 72..95)
        for (int c = tid; c < 768; c += 256) {
            int r = c / 12, cc = (c % 12) * 8;
            uint4 v = {0, 0, 0, 0};
            if (cc < 72) v = *(const uint4*)(qkv + (size_t)(k0 + r) * 3456 + 1152 + hoff + cc);
            *(uint4*)&Ks[r][cc] = v;
        }
        // stage V transposed (kv-major map -> conflict-free scalar writes)
        for (int c = tid; c < 576; c += 256) {
            int r = c & 63, cc = (c >> 6) * 8;
            uint4 v = *(const uint4*)(qkv + (size_t)(k0 + r) * 3456 + 2304 + hoff + cc);
            const bf16* e = (const bf16*)&v;
#pragma unroll
            for (int i = 0; i < 8; i++) Vs[cc + i][r] = e[i];
        }
        __syncthreads();  // barrier B: tile staged

        // S = Q K^T (raw; scale folded into exp2 below)
        f32x4 sfr[4] = {};
        __builtin_amdgcn_s_setprio(1);
#pragma unroll
        for (int kc = 0; kc < 3; kc++)
#pragma unroll
            for (int nt = 0; nt < 4; nt++) {
                bf16x8 bk = *(const bf16x8*)&Ks[nt * 16 + l15][kc * 32 + quad * 8];
                sfr[nt] = __builtin_amdgcn_mfma_f32_16x16x32_bf16(aq[kc], bk, sfr[nt], 0, 0, 0);
            }
        __builtin_amdgcn_s_setprio(0);

        // online softmax; row = quad*4+reg, 16 lanes of the quad share a row
        float mx[4];
#pragma unroll
        for (int reg = 0; reg < 4; reg++) {
            float m = fmaxf(fmaxf(sfr[0][reg], sfr[1][reg]), fmaxf(sfr[2][reg], sfr[3][reg]));
            m = fmaxf(m, __shfl_xor(m, 1));
            m = fmaxf(m, __shfl_xor(m, 2));
            m = fmaxf(m, __shfl_xor(m, 4));
            m = fmaxf(m, __shfl_xor(m, 8));
            mx[reg] = m;
        }
        // defer-max: rescale only when some row max grew (wave-uniform branch)
        bool grow = (mx[0] > m_i[0]) || (mx[1] > m_i[1]) || (mx[2] > m_i[2]) || (mx[3] > m_i[3]);
        if (__any(grow)) {
#pragma unroll
            for (int reg = 0; reg < 4; reg++) {
                float mn = fmaxf(m_i[reg], mx[reg]);
                float a = __builtin_amdgcn_exp2f((m_i[reg] - mn) * C1);
                m_i[reg] = mn;
                l_i[reg] *= a;
#pragma unroll
                for (int nt = 0; nt < 5; nt++) o[nt][reg] *= a;
            }
        }
        float mc[4];
#pragma unroll
        for (int reg = 0; reg < 4; reg++) mc[reg] = m_i[reg] * C1;
        float rs[4] = {0.f, 0.f, 0.f, 0.f};
#pragma unroll
        for (int nt = 0; nt < 4; nt++)
#pragma unroll
            for (int reg = 0; reg < 4; reg++) {
                float p = __builtin_amdgcn_exp2f(fmaf(sfr[nt][reg], C1, -mc[reg]));
                sfr[nt][reg] = p;
                rs[reg] += p;
            }
#pragma unroll
        for (int reg = 0; reg < 4; reg++) {
            float r = rs[reg];
            r += __shfl_xor(r, 1);
            r += __shfl_xor(r, 2);
            r += __shfl_xor(r, 4);
            r += __shfl_xor(r, 8);
            l_i[reg] += r;
        }

        // P: C-layout -> LDS. Ps rows [wv*16, wv*16+16) are wave-private: no barrier needed;
        // compiler-inserted lgkmcnt orders the reads below.
#pragma unroll
        for (int nt = 0; nt < 4; nt++)
#pragma unroll
            for (int reg = 0; reg < 4; reg++)
                Ps[wv * 16 + quad * 4 + reg][nt * 16 + l15] = (bf16)sfr[nt][reg];

        // O += P @ V
        __builtin_amdgcn_s_setprio(1);
#pragma unroll
        for (int kc = 0; kc < 2; kc++) {
            bf16x8 ap = *(const bf16x8*)&Ps[wv * 16 + l15][kc * 32 + quad * 8];
#pragma unroll
            for (int nt = 0; nt < 5; nt++) {
                bf16x8 bv = *(const bf16x8*)&Vs[nt * 16 + l15][kc * 32 + quad * 8];
                o[nt] = __builtin_amdgcn_mfma_f32_16x16x32_bf16(ap, bv, o[nt], 0, 0, 0);
            }
        }
        __builtin_amdgcn_s_setprio(0);
    }

#pragma unroll
    for (int nt = 0; nt < 5; nt++)
#pragma unroll
        for (int reg = 0; reg < 4; reg++) {
            int c = nt * 16 + l15;
            if (c < 72) {
                int tok = q0 + wv * 16 + quad * 4 + reg;
                outp[(size_t)tok * DMODEL + head * 72 + c] = (bf16)(o[nt][reg] / l_i[reg]);
            }
        }
}

// ---------- OLD generic GEMM + helpers (fallback path when workspace too small) ----------
template <typename TI>
__global__ __launch_bounds__(256) void pos_embed_kernel(const int* __restrict__ flag,
                                                        const TI* __restrict__ tab,
                                                        bf16* __restrict__ x) {
    if (*flag != (sizeof(TI) == 4 ? 1 : 0)) return;
    int t = blockIdx.x;
    int row, col, gh, gw;
    tok_geo(t, row, col, gh, gw);
    float hi = row * 47.0f / (gh - 1);
    float wi = col * 47.0f / (gw - 1);
    int hf = (int)hi, wf = (int)wi;
    int hc = min(hf + 1, 47), wc = min(wf + 1, 47);
    float dh = hi - hf, dw = wi - wf;
    float w00 = (1.f - dh) * (1.f - dw);
    float w01 = (1.f - dh) * dw;
    float w10 = dh * (1.f - dw);
    float w11 = dh * dw;
    const TI* p00 = tab + (size_t)(hf * 48 + wf) * DMODEL;
    const TI* p01 = tab + (size_t)(hf * 48 + wc) * DMODEL;
    const TI* p10 = tab + (size_t)(hc * 48 + wf) * DMODEL;
    const TI* p11 = tab + (size_t)(hc * 48 + wc) * DMODEL;
    bf16* xr = x + (size_t)t * DMODEL;
    for (int d = threadIdx.x; d < DMODEL; d += 256)
        xr[d] = (bf16)(w00 * (float)p00[d] + w01 * (float)p01[d] +
                       w10 * (float)p10[d] + w11 * (float)p11[d]);
}

template <typename TI>
__global__ __launch_bounds__(256) void ln_kernel(const int* __restrict__ flag,
                                                 const bf16* __restrict__ x,
                                                 const TI* __restrict__ s,
                                                 const TI* __restrict__ b,
                                                 bf16* __restrict__ out) {
    if (*flag != (sizeof(TI) == 4 ? 1 : 0)) return;
    const int row = blockIdx.x;
    const int tid = threadIdx.x;
    __shared__ float red[4];
    const bf16* xr = x + (size_t)row * DMODEL;
    float vals[5];
    int cnt = 0;
    float sum = 0.f;
    for (int i = tid; i < DMODEL; i += 256) { vals[cnt] = (float)xr[i]; sum += vals[cnt]; cnt++; }
#pragma unroll
    for (int off = 32; off > 0; off >>= 1) sum += __shfl_down(sum, off);
    if ((tid & 63) == 0) red[tid >> 6] = sum;
    __syncthreads();
    float mean = (red[0] + red[1] + red[2] + red[3]) * (1.0f / DMODEL);
    float vs = 0.f;
    for (int i = 0; i < cnt; i++) { float d = vals[i] - mean; vs += d * d; }
#pragma unroll
    for (int off = 32; off > 0; off >>= 1) vs += __shfl_down(vs, off);
    __syncthreads();
    if ((tid & 63) == 0) red[tid >> 6] = vs;
    __syncthreads();
    float var = (red[0] + red[1] + red[2] + red[3]) * (1.0f / DMODEL);
    float inv = rsqrtf(var + 1e-6f);
    int idx = 0;
    for (int i = tid; i < DMODEL; i += 256)
        out[(size_t)row * DMODEL + i] = (bf16)((vals[idx++] - mean) * inv * (float)s[i] + (float)b[i]);
}

template <int MODE, typename TA, typename TB>
__global__ __launch_bounds__(256) void gemm_kernel(const int* __restrict__ flag,
                                                   const TA* __restrict__ A,
                                                   const TB* __restrict__ B,
                                                   const TB* __restrict__ bias,
                                                   void* __restrict__ outp,
                                                   int M, int N, int K) {
    if (*flag != (sizeof(TB) == 4 ? 1 : 0)) return;
    __shared__ bf16 As[128][40];
    __shared__ bf16 Bs[128][40];
    const int tid = threadIdx.x;
    const int m0 = blockIdx.y * 128;
    const int n0 = blockIdx.x * 128;
    const int wv = tid >> 6;
    const int lane = tid & 63;
    const int quad = lane >> 4;
    const int l15 = lane & 15;
    const int wr = (wv >> 1) * 64;
    const int wc = (wv & 1) * 64;

    const int a_row = tid >> 1;
    const int a_col = (tid & 1) * 16;
    const int b_k = tid & 31;
    const int b_n = (tid >> 5) * 16;

    f32x4 acc[4][4] = {};

    for (int k0 = 0; k0 < K; k0 += 32) {
        __syncthreads();
        {
            bf16 ea[16];
            int gr = m0 + a_row;
            const TA* ap = A + (size_t)gr * K + k0 + a_col;
            load8(ap, ea, gr < M && (k0 + a_col) < K);
            load8(ap + 8, ea + 8, gr < M && (k0 + a_col + 8) < K);
            *(uint4*)&As[a_row][a_col] = *(uint4*)ea;
            *(uint4*)&As[a_row][a_col + 8] = *(uint4*)(ea + 8);
        }
        {
            bf16 eb[16];
            int gk = k0 + b_k;
            const TB* bp = B + (size_t)gk * N + n0 + b_n;
            load8(bp, eb, gk < K && (n0 + b_n) < N);
            load8(bp + 8, eb + 8, gk < K && (n0 + b_n + 8) < N);
#pragma unroll
            for (int i = 0; i < 16; i++) Bs[b_n + i][b_k] = eb[i];
        }
        __syncthreads();

        bf16x8 af[4], bfv[4];
#pragma unroll
        for (int mi = 0; mi < 4; mi++) af[mi] = *(const bf16x8*)&As[wr + mi * 16 + l15][quad * 8];
#pragma unroll
        for (int ni = 0; ni < 4; ni++) bfv[ni] = *(const bf16x8*)&Bs[wc + ni * 16 + l15][quad * 8];
#pragma unroll
        for (int mi = 0; mi < 4; mi++)
#pragma unroll
            for (int ni = 0; ni < 4; ni++)
                acc[mi][ni] = __builtin_amdgcn_mfma_f32_16x16x32_bf16(af[mi], bfv[ni], acc[mi][ni], 0, 0, 0);
    }

#pragma unroll
    for (int mi = 0; mi < 4; mi++) {
#pragma unroll
        for (int ni = 0; ni < 4; ni++) {
#pragma unroll
            for (int reg = 0; reg < 4; reg++) {
                int r = m0 + wr + mi * 16 + quad * 4 + reg;
                int c = n0 + wc + ni * 16 + l15;
                if (r < M && c < N) {
                    float v = acc[mi][ni][reg] + (float)bias[c];
                    if (MODE == 1) v = gelu_tanh(v);
                    if (MODE == 2) {
                        bf16* o = (bf16*)outp;
                        size_t idx = (size_t)r * N + c;
                        o[idx] = (bf16)((float)o[idx] + v);
                    } else if (MODE == 3) {
                        TB* o = (TB*)outp;
                        o[(size_t)r * N + c] = (TB)v;
                    } else {
                        bf16* o = (bf16*)outp;
                        o[(size_t)r * N + c] = (bf16)v;
                    }
                }
            }
        }
    }
}

// ================= pre-transposed bf16 weights + global_load_lds GEMM =================

typedef const __attribute__((address_space(1))) void* gas_ptr;
typedef __attribute__((address_space(3))) void* las_ptr;
__device__ __forceinline__ void gload16(const bf16* g, bf16* l) {
    __builtin_amdgcn_global_load_lds((gas_ptr)g, (las_ptr)l, 16, 0, 0);
}

// m97-style GEMM (BM=128): C[M,ldc] = A[M,K] @ BT[N,K]^T + bias.
// MODE 0: bf16 store; 1: bf16 gelu (zero-fills c in [N,ldc)); 2: bf16 +=; 3: store f32/bf16 by *flag
template <int MODE>
__global__ __launch_bounds__(256) void gemm_lds_kernel(const int* __restrict__ flag,
        const bf16* __restrict__ A, const bf16* __restrict__ BT,
        const bf16* __restrict__ bias, void* __restrict__ outp,
        int M, int N, int K, int ldc) {
    __shared__ bf16 As[128][32];
    __shared__ bf16 Bs[128][32];
    const int tid = threadIdx.x;
    const int m0 = blockIdx.y * 128;
    const int n0 = blockIdx.x * 128;
    const int wv = tid >> 6;
    const int lane = tid & 63;
    const int quad = lane >> 4;
    const int l15 = lane & 15;
    const int wr = (wv >> 1) * 64;
    const int wc = (wv & 1) * 64;

    const int sr = wv * 32 + (lane >> 2);
    const int sc = (lane & 3) * 8;
    const bf16* aP0 = A + (size_t)min(m0 + sr, M - 1) * K + sc;
    const bf16* aP1 = A + (size_t)min(m0 + sr + 16, M - 1) * K + sc;
    const bf16* bP0 = BT + (size_t)min(n0 + sr, N - 1) * K + sc;
    const bf16* bP1 = BT + (size_t)min(n0 + sr + 16, N - 1) * K + sc;
    bf16* lA0 = &As[wv * 32][0];
    bf16* lA1 = &As[wv * 32 + 16][0];
    bf16* lB0 = &Bs[wv * 32][0];
    bf16* lB1 = &Bs[wv * 32 + 16][0];

    f32x4 acc[4][4] = {};
    for (int k0 = 0; k0 < K; k0 += 32) {
        __syncthreads();
        gload16(aP0 + k0, lA0);
        gload16(aP1 + k0, lA1);
        gload16(bP0 + k0, lB0);
        gload16(bP1 + k0, lB1);
        __syncthreads();
        bf16x8 af[4], bfv[4];
#pragma unroll
        for (int mi = 0; mi < 4; mi++) af[mi] = *(const bf16x8*)&As[wr + mi * 16 + l15][quad * 8];
#pragma unroll
        for (int ni = 0; ni < 4; ni++) bfv[ni] = *(const bf16x8*)&Bs[wc + ni * 16 + l15][quad * 8];
#pragma unroll
        for (int mi = 0; mi < 4; mi++)
#pragma unroll
            for (int ni = 0; ni < 4; ni++)
                acc[mi][ni] = __builtin_amdgcn_mfma_f32_16x16x32_bf16(af[mi], bfv[ni], acc[mi][ni], 0, 0, 0);
    }

    const int isf32 = (MODE == 3) ? *flag : 0;
#pragma unroll
    for (int mi = 0; mi < 4; mi++) {
#pragma unroll
        for (int ni = 0; ni < 4; ni++) {
#pragma unroll
            for (int reg = 0; reg < 4; reg++) {
                int r = m0 + wr + mi * 16 + quad * 4 + reg;
                int c = n0 + wc + ni * 16 + l15;
                if (r < M && c < ldc) {
                    float v = 0.f;
                    if (c < N) {
                        v = acc[mi][ni][reg] + (float)bias[c];
                        if (MODE == 1) v = gelu_tanh(v);
                    }
                    if (MODE == 2) {
                        bf16* o = (bf16*)outp;
                        size_t idx = (size_t)r * ldc + c;
                        o[idx] = (bf16)((float)o[idx] + v);
                    } else if (MODE == 3) {
                        if (isf32) ((float*)outp)[(size_t)r * ldc + c] = v;
                        else       ((bf16*)outp)[(size_t)r * ldc + c] = (bf16)v;
                    } else {
                        ((bf16*)outp)[(size_t)r * ldc + c] = (bf16)v;
                    }
                }
            }
        }
    }
}

// BM=64 variant for grid-starved GEMMs (N small or few blocks).
template <int MODE>
__global__ __launch_bounds__(256) void gemm_lds64_kernel(const int* __restrict__ flag,
        const bf16* __restrict__ A, const bf16* __restrict__ BT,
        const bf16* __restrict__ bias, void* __restrict__ outp,
        int M, int N, int K, int ldc) {
    __shared__ bf16 As[64][32];
    __shared__ bf16 Bs[128][32];
    const int tid = threadIdx.x;
    const int m0 = blockIdx.y * 64;
    const int n0 = blockIdx.x * 128;
    const int wv = tid >> 6;
    const int lane = tid & 63;
    const int quad = lane >> 4;
    const int l15 = lane & 15;
    const int wr = (wv >> 1) * 32;
    const int wc = (wv & 1) * 64;

    const int sc = (lane & 3) * 8;
    const int srA = wv * 16 + (lane >> 2);
    const int srB = wv * 32 + (lane >> 2);
    const bf16* aP0 = A + (size_t)min(m0 + srA, M - 1) * K + sc;
    const bf16* bP0 = BT + (size_t)min(n0 + srB, N - 1) * K + sc;
    const bf16* bP1 = BT + (size_t)min(n0 + srB + 16, N - 1) * K + sc;
    bf16* lA0 = &As[wv * 16][0];
    bf16* lB0 = &Bs[wv * 32][0];
    bf16* lB1 = &Bs[wv * 32 + 16][0];

    f32x4 acc[2][4] = {};
    for (int k0 = 0; k0 < K; k0 += 32) {
        __syncthreads();
        gload16(aP0 + k0, lA0);
        gload16(bP0 + k0, lB0);
        gload16(bP1 + k0, lB1);
        __syncthreads();
        bf16x8 af[2], bfv[4];
#pragma unroll
        for (int mi = 0; mi < 2; mi++) af[mi] = *(const bf16x8*)&As[wr + mi * 16 + l15][quad * 8];
#pragma unroll
        for (int ni = 0; ni < 4; ni++) bfv[ni] = *(const bf16x8*)&Bs[wc + ni * 16 + l15][quad * 8];
#pragma unroll
        for (int mi = 0; mi < 2; mi++)
#pragma unroll
            for (int ni = 0; ni < 4; ni++)
                acc[mi][ni] = __builtin_amdgcn_mfma_f32_16x16x32_bf16(af[mi], bfv[ni], acc[mi][ni], 0, 0, 0);
    }

    const int isf32 = (MODE == 3) ? *flag : 0;
#pragma unroll
    for (int mi = 0; mi < 2; mi++) {
#pragma unroll
        for (int ni = 0; ni < 4; ni++) {
#pragma unroll
            for (int reg = 0; reg < 4; reg++) {
                int r = m0 + wr + mi * 16 + quad * 4 + reg;
                int c = n0 + wc + ni * 16 + l15;
                if (r < M && c < ldc) {
                    float v = 0.f;
                    if (c < N) {
                        v = acc[mi][ni][reg] + (float)bias[c];
                        if (MODE == 1) v = gelu_tanh(v);
                    }
                    if (MODE == 2) {
                        bf16* o = (bf16*)outp;
                        size_t idx = (size_t)r * ldc + c;
                        o[idx] = (bf16)((float)o[idx] + v);
                    } else if (MODE == 3) {
                        if (isf32) ((float*)outp)[(size_t)r * ldc + c] = v;
                        else       ((bf16*)outp)[(size_t)r * ldc + c] = (bf16)v;
                    } else {
                        ((bf16*)outp)[(size_t)r * ldc + c] = (bf16)v;
                    }
                }
            }
        }
    }
}

// ---------- arena layout (bf16 elements) ----------
#define OFF_PATCH  0ULL
#define OFF_QKV    1769472ULL
#define QKV_SZ     3981312ULL
#define OFF_PROJ   9732096ULL
#define PROJ_SZ    1327104ULL
#define OFF_FC1    12386304ULL
#define FC1_SZ     4958208ULL
#define OFF_FC2    22302720ULL
#define FC2_SZ     4976640ULL
#define OFF_MFC1   32256000ULL
#define OFF_MFC2   53489664ULL
#define OFF_BIAS   62926848ULL
#define WS_NEEDED  209001280ULL

extern "C" void kernel_launch(void* const* d_in, const int* in_sizes, int n_in,
                              void* d_out, int out_size, void* d_ws, size_t ws_size,
                              hipStream_t stream) {
    char* ws = (char*)d_ws;
    int* flag  = (int*)ws;                       // 256 B reserved
    bf16* x    = (bf16*)(ws + 256);              // 14,450,688 B
    bf16* h    = (bf16*)(ws + 256 + 14450688);   // 14,450,688 B
    bf16* bufA = (bf16*)(ws + 256 + 28901376);   // 54,190,080 B (6272*4320*2)

    detect_kernel<<<1, 64, 0, stream>>>((const unsigned short*)d_in[0], flag);

    if (ws_size >= WS_NEEDED) {
        // ---------------- NEW PATH (fused-dtype launches) ----------------
        bf16* wT = (bf16*)(ws + 256 + 28901376 + 54190080);
        bf16* bias = wT + OFF_BIAS;
        bf16* px = bufA;  // pixels-as-bf16 live in bufA until the patch GEMM is done

        // pixel convert (6272*1536 / 8 = 1,204,224 chunks)
        cvt2_kernel<<<1024, 256, 0, stream>>>(flag, (const bf16*)d_in[0], (const float*)d_in[0],
                                              px, 1204224);

        // weight transposes (single launch each, runtime dtype branch)
        auto T1 = [&](const void* srcBase, size_t eoff, bf16* dst, int K, int N, int Kpad) {
            dim3 g((N + 63) / 64, (Kpad + 63) / 64);
            transpose_w2_kernel<<<g, 256, 0, stream>>>(flag, (const bf16*)srcBase + eoff,
                                                       (const float*)srcBase + eoff, dst, K, N, Kpad);
        };
        T1(d_in[2], 0, wT + OFF_PATCH, 1536, 1152, 1536);
        for (int l = 0; l < 2; l++) {
            T1(d_in[7],  (size_t)l * 1152 * 3456, wT + OFF_QKV + l * QKV_SZ, 1152, 3456, 1152);
            T1(d_in[9],  (size_t)l * 1152 * 1152, wT + OFF_PROJ + l * PROJ_SZ, 1152, 1152, 1152);
            T1(d_in[13], (size_t)l * 1152 * 4304, wT + OFF_FC1 + l * FC1_SZ, 1152, 4304, 1152);
            T1(d_in[15], (size_t)l * 4304 * 1152, wT + OFF_FC2 + l * FC2_SZ, 4304, 1152, 4320);
        }
        T1(d_in[19], 0, wT + OFF_MFC1, 4608, 4608, 4608);
        T1(d_in[21], 0, wT + OFF_MFC2, 4608, 2048, 4608);

        cvt_bias_kernel<bf16><<<11, 256, 0, stream>>>(flag,
            (const bf16*)d_in[3],
            (const bf16*)d_in[8], (const bf16*)d_in[8] + 3456,
            (const bf16*)d_in[10], (const bf16*)d_in[10] + 1152,
            (const bf16*)d_in[14], (const bf16*)d_in[14] + 4304,
            (const bf16*)d_in[16], (const bf16*)d_in[16] + 1152,
            (const bf16*)d_in[20], (const bf16*)d_in[22], bias);
        cvt_bias_kernel<float><<<11, 256, 0, stream>>>(flag,
            (const float*)d_in[3],
            (const float*)d_in[8], (const float*)d_in[8] + 3456,
            (const float*)d_in[10], (const float*)d_in[10] + 1152,
            (const float*)d_in[14], (const float*)d_in[14] + 4304,
            (const float*)d_in[16], (const float*)d_in[16] + 1152,
            (const float*)d_in[20], (const float*)d_in[22], bias);

        pos_embed2_kernel<<<NTOK, 256, 0, stream>>>(flag, (const bf16*)d_in[4],
                                                    (const float*)d_in[4], x);

        gemm_lds64_kernel<2><<<dim3(9, 98), 256, 0, stream>>>(flag, px, wT + OFF_PATCH,
                                                              bias + 0, x, NTOK, 1152, 1536, 1152);

        for (int l = 0; l < 2; l++) {
            ln2_kernel<<<NTOK, 256, 0, stream>>>(flag, x,
                (const bf16*)d_in[5] + l * 1152, (const bf16*)d_in[6] + l * 1152,
                (const float*)d_in[5] + l * 1152, (const float*)d_in[6] + l * 1152, h);
            gemm_lds_kernel<0><<<dim3(27, 49), 256, 0, stream>>>(flag, h, wT + OFF_QKV + l * QKV_SZ,
                                                                 bias + 1152 + l * 3456, bufA,
                                                                 NTOK, 3456, 1152, 3456);
            rope_inplace_kernel<<<(NTOK * 16 * 36 + 255) / 256, 256, 0, stream>>>(bufA);
            attn_kernel<<<98 * 16, 256, 0, stream>>>(bufA, h);
            gemm_lds64_kernel<2><<<dim3(9, 98), 256, 0, stream>>>(flag, h, wT + OFF_PROJ + l * PROJ_SZ,
                                                                  bias + 8064 + l * 1152, x,
                                                                  NTOK, 1152, 1152, 1152);
            ln2_kernel<<<NTOK, 256, 0, stream>>>(flag, x,
                (const bf16*)d_in[11] + l * 1152, (const bf16*)d_in[12] + l * 1152,
                (const float*)d_in[11] + l * 1152, (const float*)d_in[12] + l * 1152, h);
            // fc1: ldc=4320, zero-fills pad cols so fc2 can run K=4320
            gemm_lds_kernel<1><<<dim3(34, 49), 256, 0, stream>>>(flag, h, wT + OFF_FC1 + l * FC1_SZ,
                                                                 bias + 10368 + l * 4304, bufA,
                                                                 NTOK, 4304, 1152, 4320);
            gemm_lds64_kernel<2><<<dim3(9, 98), 256, 0, stream>>>(flag, bufA, wT + OFF_FC2 + l * FC2_SZ,
                                                                  bias + 18976 + l * 1152, x,
                                                                  NTOK, 1152, 4320, 1152);
        }
        ln2_kernel<<<NTOK, 256, 0, stream>>>(flag, x,
            (const bf16*)d_in[17], (const bf16*)d_in[18],
            (const float*)d_in[17], (const float*)d_in[18], h);
        gemm_lds64_kernel<1><<<dim3(36, 25), 256, 0, stream>>>(flag, h, wT + OFF_MFC1,
                                                               bias + 21280, bufA, 1568, 4608, 4608, 4608);
        gemm_lds64_kernel<3><<<dim3(16, 25), 256, 0, stream>>>(flag, bufA, wT + OFF_MFC2,
                                                               bias + 25888, d_out, 1568, 2048, 4608, 2048);
        return;
    }

    // ---------------- FALLBACK: round-1 verified path ----------------
    {
        pos_embed_kernel<bf16><<<NTOK, 256, 0, stream>>>(flag, (const bf16*)d_in[4], x);
        pos_embed_kernel<float><<<NTOK, 256, 0, stream>>>(flag, (const float*)d_in[4], x);
        gemm_kernel<2, bf16, bf16><<<dim3(9, 49), 256, 0, stream>>>(
            flag, (const bf16*)d_in[0], (const bf16*)d_in[2], (const bf16*)d_in[3], x, NTOK, 1152, 1536);
        gemm_kernel<2, float, float><<<dim3(9, 49), 256, 0, stream>>>(
            flag, (const float*)d_in[0], (const float*)d_in[2], (const float*)d_in[3], x, NTOK, 1152, 1536);
    }
    for (int l = 0; l < 2; l++) {
        ln_kernel<bf16><<<NTOK, 256, 0, stream>>>(flag, x, (const bf16*)d_in[5] + l * 1152,
                                                  (const bf16*)d_in[6] + l * 1152, h);
        ln_kernel<float><<<NTOK, 256, 0, stream>>>(flag, x, (const float*)d_in[5] + l * 1152,
                                                   (const float*)d_in[6] + l * 1152, h);
        gemm_kernel<0, bf16, bf16><<<dim3(27, 49), 256, 0, stream>>>(
            flag, h, (const bf16*)d_in[7] + (size_t)l * 1152 * 3456,
            (const bf16*)d_in[8] + l * 3456, bufA, NTOK, 3456, 1152);
        gemm_kernel<0, bf16, float><<<dim3(27, 49), 256, 0, stream>>>(
            flag, h, (const float*)d_in[7] + (size_t)l * 1152 * 3456,
            (const float*)d_in[8] + l * 3456, bufA, NTOK, 3456, 1152);
        rope_inplace_kernel<<<(NTOK * 16 * 36 + 255) / 256, 256, 0, stream>>>(bufA);
        attn_kernel<<<98 * 16, 256, 0, stream>>>(bufA, h);
        gemm_kernel<2, bf16, bf16><<<dim3(9, 49), 256, 0, stream>>>(
            flag, h, (const bf16*)d_in[9] + (size_t)l * 1152 * 1152,
            (const bf16*)d_in[10] + l * 1152, x, NTOK, 1152, 1152);
        gemm_kernel<2, bf16, float><<<dim3(9, 49), 256, 0, stream>>>(
            flag, h, (const float*)d_in[9] + (size_t)l * 1152 * 1152,
            (const float*)d_in[10] + l * 1152, x, NTOK, 1152, 1152);
        ln_kernel<bf16><<<NTOK, 256, 0, stream>>>(flag, x, (const bf16*)d_in[11] + l * 1152,
                                                  (const bf16*)d_in[12] + l * 1152, h);
        ln_kernel<float><<<NTOK, 256, 0, stream>>>(flag, x, (const float*)d_in[11] + l * 1152,
                                                   (const float*)d_in[12] + l * 1152, h);
        gemm_kernel<1, bf16, bf16><<<dim3(34, 49), 256, 0, stream>>>(
            flag, h, (const bf16*)d_in[13] + (size_t)l * 1152 * 4304,
            (const bf16*)d_in[14] + l * 4304, bufA, NTOK, 4304, 1152);
        gemm_kernel<1, bf16, float><<<dim3(34, 49), 256, 0, stream>>>(
            flag, h, (const float*)d_in[13] + (size_t)l * 1152 * 4304,
            (const float*)d_in[14] + l * 4304, bufA, NTOK, 4304, 1152);
        gemm_kernel<2, bf16, bf16><<<dim3(9, 49), 256, 0, stream>>>(
            flag, bufA, (const bf16*)d_in[15] + (size_t)l * 4304 * 1152,
            (const bf16*)d_in[16] + l * 1152, x, NTOK, 1152, 4304);
        gemm_kernel<2, bf16, float><<<dim3(9, 49), 256, 0, stream>>>(
            flag, bufA, (const float*)d_in[15] + (size_t)l * 4304 * 1152,
            (const float*)d_in[16] + l * 1152, x, NTOK, 1152, 4304);
    }
    ln_kernel<bf16><<<NTOK, 256, 0, stream>>>(flag, x, (const bf16*)d_in[17], (const bf16*)d_in[18], h);
    ln_kernel<float><<<NTOK, 256, 0, stream>>>(flag, x, (const float*)d_in[17], (const float*)d_in[18], h);
    gemm_kernel<1, bf16, bf16><<<dim3(36, 13), 256, 0, stream>>>(
        flag, h, (const bf16*)d_in[19], (const bf16*)d_in[20], bufA, 1568, 4608, 4608);
    gemm_kernel<1, bf16, float><<<dim3(36, 13), 256, 0, stream>>>(
        flag, h, (const float*)d_in[19], (const float*)d_in[20], bufA, 1568, 4608, 4608);
    gemm_kernel<3, bf16, bf16><<<dim3(16, 13), 256, 0, stream>>>(
        flag, bufA, (const bf16*)d_in[21], (const bf16*)d_in[22], d_out, 1568, 2048, 4608);
    gemm_kernel<3, bf16, float><<<dim3(16, 13), 256, 0, stream>>>(
        flag, bufA, (const float*)d_in[21], (const float*)d_in[22], d_out, 1568, 2048, 4608);
}